// Round 2
// baseline (54132.507 us; speedup 1.0000x reference)
//
#include <hip/hip_runtime.h>
#include <math.h>

#define NPT 4096      // points per image (64x64)
#define CCH 512       // channels
#define NB 64         // cholesky panel size
#define NKB 64        // NPT / NB
#define LDB 4160      // RHS leading dim = NPT + 64 feature cols
#define SIGF 0.1f
#define CEPS 1e-6f
#define PI8 25.132741228718345f   // 8*pi

// ---------------- norms: nrm[slot][p] = ||X[slot+bofs,:,p]|| ----------------
__global__ __launch_bounds__(256) void norms_kernel(const float* __restrict__ X,
                                                    float* __restrict__ nrm, int bofs) {
    int slot = blockIdx.y;
    int p = blockIdx.x * 256 + threadIdx.x;
    const float* Xb = X + (size_t)(slot + bofs) * CCH * NPT;
    float s = 0.f;
    #pragma unroll 8
    for (int ch = 0; ch < CCH; ++ch) {
        float v = Xb[(size_t)ch * NPT + p];
        s += v * v;
    }
    nrm[slot * NPT + p] = sqrtf(s);
}

// ------------- cosgram: C[m,n] = exp(colA_m . colB_n / (nA nB + eps) - 1) -------------
__global__ __launch_bounds__(256) void cosgram_kernel(
    const float* __restrict__ A, const float* __restrict__ B,
    const float* __restrict__ nA, const float* __restrict__ nB,
    float* __restrict__ Cm, int ldc, size_t cBatchStride, int addDiag, int bofs)
{
    int slot = blockIdx.z;
    const float* Ab = A + (size_t)(slot + bofs) * CCH * NPT;
    const float* Bb = B + (size_t)(slot + bofs) * CCH * NPT;
    const float* nAb = nA + slot * NPT;
    const float* nBb = nB + slot * NPT;
    float* Cb = Cm + (size_t)slot * cBatchStride;
    int bm = blockIdx.y * 64, bn = blockIdx.x * 64;
    __shared__ float As[16][64];
    __shared__ float Bs[16][64];
    float acc[4][4] = {};
    int tid = threadIdx.x, tx = tid & 15, ty = tid >> 4;
    int lm = tid & 63, lk = tid >> 6;
    for (int k0 = 0; k0 < CCH; k0 += 16) {
        #pragma unroll
        for (int r = 0; r < 4; ++r) {
            As[lk + r * 4][lm] = Ab[(size_t)(k0 + lk + r * 4) * NPT + bm + lm];
            Bs[lk + r * 4][lm] = Bb[(size_t)(k0 + lk + r * 4) * NPT + bn + lm];
        }
        __syncthreads();
        #pragma unroll
        for (int kk = 0; kk < 16; ++kk) {
            float av[4], bv[4];
            #pragma unroll
            for (int i = 0; i < 4; ++i) { av[i] = As[kk][ty * 4 + i]; bv[i] = Bs[kk][tx * 4 + i]; }
            #pragma unroll
            for (int i = 0; i < 4; ++i)
                #pragma unroll
                for (int j = 0; j < 4; ++j) acc[i][j] += av[i] * bv[j];
        }
        __syncthreads();
    }
    float na[4], nb_[4];
    #pragma unroll
    for (int i = 0; i < 4; ++i) { na[i] = nAb[bm + ty * 4 + i]; nb_[i] = nBb[bn + tx * 4 + i]; }
    #pragma unroll
    for (int i = 0; i < 4; ++i)
        #pragma unroll
        for (int j = 0; j < 4; ++j) {
            int m = bm + ty * 4 + i, n = bn + tx * 4 + j;
            float v = expf(acc[i][j] / (na[i] * nb_[j] + CEPS) - 1.0f);
            if (addDiag && m == n) v += SIGF;
            Cb[(size_t)m * ldc + n] = v;
        }
}

// ------------- features: Brhs[slot][q][NPT+dd] = cos(8pi(pw0*gx + pw1*gy + pb)) -------------
__global__ __launch_bounds__(256) void features_kernel(const float* __restrict__ pw,
                                                       const float* __restrict__ pb,
                                                       float* __restrict__ Brhs) {
    int slot = blockIdx.y;
    int g = blockIdx.x * 256 + threadIdx.x;   // 0 .. 262143
    int q = g >> 6, dd = g & 63;
    int hh = q >> 6, ww = q & 63;
    float gy = -1.0f + (2 * hh + 1) / 64.0f;
    float gx = -1.0f + (2 * ww + 1) / 64.0f;
    float ph = PI8 * (pw[dd * 2 + 0] * gx + pw[dd * 2 + 1] * gy + pb[dd]);
    Brhs[(size_t)slot * NPT * LDB + (size_t)q * LDB + NPT + dd] = cosf(ph);
}

// ------------- potf2: factor NB x NB diag block, also produce inv(L_kk) -------------
__global__ __launch_bounds__(256) void potf2_kernel(float* __restrict__ Amat,
                                                    float* __restrict__ invL, int kb) {
    __shared__ float a[NB][NB + 4];
    __shared__ float iv[NB][NB + 4];
    __shared__ float ddiag[NB];
    int slot = blockIdx.z;
    float* Ab = Amat + (size_t)slot * NPT * NPT + ((size_t)kb * NB) * NPT + (size_t)kb * NB;
    int tid = threadIdx.x;
    int tx = tid & 15, ty = tid >> 4;
    for (int t = tid; t < NB * NB; t += 256) {
        int i = t >> 6, j = t & 63;
        a[i][j] = Ab[(size_t)i * NPT + j];
        iv[i][j] = 0.0f;
    }
    __syncthreads();
    for (int j = 0; j < NB; ++j) {
        float ajj = sqrtf(a[j][j]);
        float dinv = 1.0f / ajj;
        if (tid == 0) ddiag[j] = ajj;
        for (int i = j + 1 + tid; i < NB; i += 256) a[i][j] *= dinv;
        for (int c = tid; c <= j; c += 256)
            iv[j][c] = ((c == j ? 1.0f : 0.0f) - iv[j][c]) * dinv;
        __syncthreads();
        for (int i = j + 1 + ty; i < NB; i += 16) {
            float lij = a[i][j];
            for (int jj = j + 1 + tx; jj < NB; jj += 16)
                a[i][jj] -= lij * a[jj][j];
            for (int c = tx; c <= j; c += 16)
                iv[i][c] += lij * iv[j][c];
        }
        __syncthreads();
    }
    float* iL = invL + ((size_t)slot * NKB + kb) * (NB * NB);
    for (int t = tid; t < NB * NB; t += 256) {
        int i = t >> 6, j = t & 63;
        if (j < i)       Ab[(size_t)i * NPT + j] = a[i][j];
        else if (j == i) Ab[(size_t)i * NPT + j] = ddiag[i];
        iL[t] = (j <= i) ? iv[i][j] : 0.0f;
    }
}

// ------------- trsm_panel: panel rows (below diag) = panel @ invL^T -------------
__global__ __launch_bounds__(256) void trsm_panel_kernel(float* __restrict__ Amat,
                                                         const float* __restrict__ invL, int kb) {
    int slot = blockIdx.z;
    int r0 = (kb + 1) * NB + blockIdx.x * 64;
    int pcol = kb * NB;
    float* Ab = Amat + (size_t)slot * NPT * NPT;
    const float* iL = invL + ((size_t)slot * NKB + kb) * (NB * NB);
    __shared__ float Ao[64][NB + 1];
    __shared__ float Ls[NB][17];
    float acc[4][4] = {};
    int tid = threadIdx.x, tx = tid & 15, ty = tid >> 4;
    for (int t = tid; t < 64 * NB; t += 256) {
        int i = t >> 6, k = t & 63;
        Ao[i][k] = Ab[(size_t)(r0 + i) * NPT + pcol + k];
    }
    for (int k0 = 0; k0 < NB; k0 += 16) {
        for (int t = tid; t < NB * 16; t += 256) {
            int j = t >> 4, kk = t & 15;
            Ls[j][kk] = iL[j * NB + k0 + kk];
        }
        __syncthreads();
        #pragma unroll
        for (int kk = 0; kk < 16; ++kk) {
            float av[4], lv[4];
            #pragma unroll
            for (int i = 0; i < 4; ++i) { av[i] = Ao[ty * 4 + i][k0 + kk]; lv[i] = Ls[tx * 4 + i][kk]; }
            #pragma unroll
            for (int i = 0; i < 4; ++i)
                #pragma unroll
                for (int j = 0; j < 4; ++j) acc[i][j] += av[i] * lv[j];
        }
        __syncthreads();
    }
    #pragma unroll
    for (int i = 0; i < 4; ++i)
        #pragma unroll
        for (int j = 0; j < 4; ++j)
            Ab[(size_t)(r0 + ty * 4 + i) * NPT + pcol + tx * 4 + j] = acc[i][j];
}

// ------------- syrk: trailing update A[i,j] -= P_i . P_j (lower tiles only) -------------
__global__ __launch_bounds__(256) void syrk_kernel(float* __restrict__ Amat, int kb) {
    int bi = blockIdx.y, bj = blockIdx.x;
    if (bj > bi) return;
    int slot = blockIdx.z;
    int off = (kb + 1) * NB;
    int pcol = kb * NB;
    float* Ab = Amat + (size_t)slot * NPT * NPT;
    int i0 = off + bi * 64, j0 = off + bj * 64;
    __shared__ float Pi[64][17];
    __shared__ float Pj[64][17];
    float acc[4][4] = {};
    int tid = threadIdx.x, tx = tid & 15, ty = tid >> 4;
    for (int k0 = 0; k0 < NB; k0 += 16) {
        for (int t = tid; t < 64 * 16; t += 256) {
            int r = t >> 4, kk = t & 15;
            Pi[r][kk] = Ab[(size_t)(i0 + r) * NPT + pcol + k0 + kk];
            Pj[r][kk] = Ab[(size_t)(j0 + r) * NPT + pcol + k0 + kk];
        }
        __syncthreads();
        #pragma unroll
        for (int kk = 0; kk < 16; ++kk) {
            float av[4], bv[4];
            #pragma unroll
            for (int i = 0; i < 4; ++i) { av[i] = Pi[ty * 4 + i][kk]; bv[i] = Pj[tx * 4 + i][kk]; }
            #pragma unroll
            for (int i = 0; i < 4; ++i)
                #pragma unroll
                for (int j = 0; j < 4; ++j) acc[i][j] += av[i] * bv[j];
        }
        __syncthreads();
    }
    #pragma unroll
    for (int i = 0; i < 4; ++i)
        #pragma unroll
        for (int j = 0; j < 4; ++j)
            Ab[(size_t)(i0 + ty * 4 + i) * NPT + j0 + tx * 4 + j] -= acc[i][j];
}

// ------------- solve_gemm: Brhs rows[kb] -= L[kb, 0:K] @ Brhs[0:K, :] -------------
__global__ __launch_bounds__(256) void solve_gemm_kernel(const float* __restrict__ Amat,
                                                         float* __restrict__ Brhs, int kb) {
    int slot = blockIdx.z;
    int rb = kb * NB;
    const float* Ab = Amat + (size_t)slot * NPT * NPT;
    float* Bb = Brhs + (size_t)slot * NPT * LDB;
    int n0 = blockIdx.x * 64;
    int K = rb;
    __shared__ float As_[64][17];
    __shared__ float Bs_[16][65];
    float acc[4][4] = {};
    int tid = threadIdx.x, tx = tid & 15, ty = tid >> 4;
    for (int k0 = 0; k0 < K; k0 += 16) {
        for (int t = tid; t < 1024; t += 256) {
            int r = t >> 4, kk = t & 15;
            As_[r][kk] = Ab[(size_t)(rb + r) * NPT + k0 + kk];
        }
        for (int t = tid; t < 1024; t += 256) {
            int kk = t >> 6, c = t & 63;
            Bs_[kk][c] = Bb[(size_t)(k0 + kk) * LDB + n0 + c];
        }
        __syncthreads();
        #pragma unroll
        for (int kk = 0; kk < 16; ++kk) {
            float av[4], bv[4];
            #pragma unroll
            for (int i = 0; i < 4; ++i) { av[i] = As_[ty * 4 + i][kk]; bv[i] = Bs_[kk][tx * 4 + i]; }
            #pragma unroll
            for (int i = 0; i < 4; ++i)
                #pragma unroll
                for (int j = 0; j < 4; ++j) acc[i][j] += av[i] * bv[j];
        }
        __syncthreads();
    }
    #pragma unroll
    for (int i = 0; i < 4; ++i)
        #pragma unroll
        for (int j = 0; j < 4; ++j)
            Bb[(size_t)(rb + ty * 4 + i) * LDB + n0 + tx * 4 + j] -= acc[i][j];
}

// ------------- trsm_apply: Brhs rows[kb] = invL_kb @ Brhs rows[kb] -------------
__global__ __launch_bounds__(256) void trsm_apply_kernel(float* __restrict__ Brhs,
                                                         const float* __restrict__ invL, int kb) {
    int slot = blockIdx.z;
    int rb = kb * NB;
    float* Bb = Brhs + (size_t)slot * NPT * LDB;
    const float* iL = invL + ((size_t)slot * NKB + kb) * (NB * NB);
    int n0 = blockIdx.x * 64;
    __shared__ float Ts[NB][65];
    __shared__ float Ls[NB][33];
    float acc[4][4] = {};
    int tid = threadIdx.x, tx = tid & 15, ty = tid >> 4;
    for (int t = tid; t < NB * 64; t += 256) {
        int r = t >> 6, c = t & 63;
        Ts[r][c] = Bb[(size_t)(rb + r) * LDB + n0 + c];
    }
    for (int k0 = 0; k0 < NB; k0 += 32) {
        for (int t = tid; t < NB * 32; t += 256) {
            int r = t >> 5, kk = t & 31;
            Ls[r][kk] = iL[r * NB + k0 + kk];
        }
        __syncthreads();
        #pragma unroll
        for (int kk = 0; kk < 32; ++kk) {
            float tv[4], lv[4];
            #pragma unroll
            for (int i = 0; i < 4; ++i) { tv[i] = Ts[k0 + kk][tx * 4 + i]; lv[i] = Ls[ty * 4 + i][kk]; }
            #pragma unroll
            for (int i = 0; i < 4; ++i)
                #pragma unroll
                for (int j = 0; j < 4; ++j) acc[i][j] += lv[i] * tv[j];
        }
        __syncthreads();
    }
    #pragma unroll
    for (int i = 0; i < 4; ++i)
        #pragma unroll
        for (int j = 0; j < 4; ++j)
            Bb[(size_t)(rb + ty * 4 + i) * LDB + n0 + tx * 4 + j] = acc[i][j];
}

// ------------- mu: out[slot+bofs, dd, p] = sum_q U[q,p] * V[q,dd] -------------
__global__ __launch_bounds__(256) void mu_kernel(const float* __restrict__ Brhs,
                                                 float* __restrict__ out, int bofs) {
    int slot = blockIdx.z;
    const float* Bb = Brhs + (size_t)slot * NPT * LDB;
    int p0 = blockIdx.x * 64;
    __shared__ float Us[16][65];
    __shared__ float Vs[16][65];
    float acc[4][4] = {};
    int tid = threadIdx.x, tx = tid & 15, ty = tid >> 4;
    for (int q0 = 0; q0 < NPT; q0 += 16) {
        for (int t = tid; t < 1024; t += 256) {
            int kk = t >> 6, c = t & 63;
            Us[kk][c] = Bb[(size_t)(q0 + kk) * LDB + p0 + c];
            Vs[kk][c] = Bb[(size_t)(q0 + kk) * LDB + NPT + c];
        }
        __syncthreads();
        #pragma unroll
        for (int kk = 0; kk < 16; ++kk) {
            float uv[4], vv[4];
            #pragma unroll
            for (int i = 0; i < 4; ++i) { uv[i] = Us[kk][ty * 4 + i]; vv[i] = Vs[kk][tx * 4 + i]; }
            #pragma unroll
            for (int i = 0; i < 4; ++i)
                #pragma unroll
                for (int j = 0; j < 4; ++j) acc[i][j] += uv[i] * vv[j];
        }
        __syncthreads();
    }
    #pragma unroll
    for (int i = 0; i < 4; ++i)
        #pragma unroll
        for (int j = 0; j < 4; ++j)
            out[((size_t)(slot + bofs) * 89 + tx * 4 + j) * NPT + p0 + ty * 4 + i] = acc[i][j];
}

// ------------- kxx_local: tmp[slot][j][p] = K_xx[p, neighbor_j(p)] (0 if OOB) -------------
__global__ __launch_bounds__(256) void kxx_local_kernel(const float* __restrict__ X,
                                                        const float* __restrict__ nx,
                                                        float* __restrict__ tmp, int bofs) {
    int slot = blockIdx.z;
    int r = blockIdx.y;
    int c0 = blockIdx.x * 16;
    const float* Xb = X + (size_t)(slot + bofs) * CCH * NPT;
    const float* nxb = nx + slot * NPT;
    __shared__ float Xs[32][104];
    int tid = threadIdx.x;
    int t0 = tid, t1 = tid + 256;
    int pl0 = t0 / 25, jj0 = t0 % 25;
    int pl1 = t1 / 25, jj1 = t1 % 25;
    int pidx0 = 40 + pl0 + 2;
    int jidx0 = (jj0 / 5) * 20 + pl0 + (jj0 % 5);
    int pidx1 = 40 + pl1 + 2;
    int jidx1 = (jj1 / 5) * 20 + pl1 + (jj1 % 5);
    float acc0 = 0.f, acc1 = 0.f;
    for (int ch0 = 0; ch0 < CCH; ch0 += 32) {
        for (int t = tid; t < 32 * 100; t += 256) {
            int ch = t / 100, i = t % 100;
            int s = i / 20, cc = i % 20;
            int gr = r + s - 2, gc = c0 - 2 + cc;
            float v = 0.f;
            if (gr >= 0 && gr < 64 && gc >= 0 && gc < 64)
                v = Xb[(size_t)(ch0 + ch) * NPT + gr * 64 + gc];
            Xs[ch][i] = v;
        }
        __syncthreads();
        #pragma unroll 8
        for (int kk = 0; kk < 32; ++kk) {
            acc0 += Xs[kk][pidx0] * Xs[kk][jidx0];
            if (t1 < 400) acc1 += Xs[kk][pidx1] * Xs[kk][jidx1];
        }
        __syncthreads();
    }
    {
        int p = r * 64 + c0 + pl0;
        int qr = r + jj0 / 5 - 2, qc = c0 + pl0 + jj0 % 5 - 2;
        float v = 0.f;
        if (qr >= 0 && qr < 64 && qc >= 0 && qc < 64) {
            int q = qr * 64 + qc;
            v = expf(acc0 / (nxb[p] * nxb[q] + CEPS) - 1.0f);
        }
        tmp[((size_t)slot * 25 + jj0) * NPT + p] = v;
    }
    if (t1 < 400) {
        int p = r * 64 + c0 + pl1;
        int qr = r + jj1 / 5 - 2, qc = c0 + pl1 + jj1 % 5 - 2;
        float v = 0.f;
        if (qr >= 0 && qr < 64 && qc >= 0 && qc < 64) {
            int q = qr * 64 + qc;
            v = expf(acc1 / (nxb[p] * nxb[q] + CEPS) - 1.0f);
        }
        tmp[((size_t)slot * 25 + jj1) * NPT + p] = v;
    }
}

// ------------- cov_local: out[slot+bofs, 64+j, p] = tmp[j,p] - U[:,p].U[:,q_j] -------------
__global__ __launch_bounds__(256) void cov_local_kernel(const float* __restrict__ Brhs,
                                                        const float* __restrict__ tmp,
                                                        float* __restrict__ out, int bofs) {
    int slot = blockIdx.z;
    int r = blockIdx.y;
    int c0 = blockIdx.x * 16;
    const float* Ub = Brhs + (size_t)slot * NPT * LDB;
    __shared__ float Us[64][104];
    int tid = threadIdx.x;
    int t0 = tid, t1 = tid + 256;
    int pl0 = t0 / 25, jj0 = t0 % 25;
    int pl1 = t1 / 25, jj1 = t1 % 25;
    int pidx0 = 40 + pl0 + 2;
    int jidx0 = (jj0 / 5) * 20 + pl0 + (jj0 % 5);
    int pidx1 = 40 + pl1 + 2;
    int jidx1 = (jj1 / 5) * 20 + pl1 + (jj1 % 5);
    float acc0 = 0.f, acc1 = 0.f;
    for (int q0 = 0; q0 < NPT; q0 += 64) {
        for (int t = tid; t < 64 * 100; t += 256) {
            int qq = t / 100, i = t % 100;
            int s = i / 20, cc = i % 20;
            int gr = r + s - 2, gc = c0 - 2 + cc;
            float v = 0.f;
            if (gr >= 0 && gr < 64 && gc >= 0 && gc < 64)
                v = Ub[(size_t)(q0 + qq) * LDB + gr * 64 + gc];
            Us[qq][i] = v;
        }
        __syncthreads();
        #pragma unroll 8
        for (int kk = 0; kk < 64; ++kk) {
            acc0 += Us[kk][pidx0] * Us[kk][jidx0];
            if (t1 < 400) acc1 += Us[kk][pidx1] * Us[kk][jidx1];
        }
        __syncthreads();
    }
    {
        int p = r * 64 + c0 + pl0;
        int qr = r + jj0 / 5 - 2, qc = c0 + pl0 + jj0 % 5 - 2;
        float v = 0.f;
        if (qr >= 0 && qr < 64 && qc >= 0 && qc < 64)
            v = tmp[((size_t)slot * 25 + jj0) * NPT + p] - acc0;
        out[((size_t)(slot + bofs) * 89 + 64 + jj0) * NPT + p] = v;
    }
    if (t1 < 400) {
        int p = r * 64 + c0 + pl1;
        int qr = r + jj1 / 5 - 2, qc = c0 + pl1 + jj1 % 5 - 2;
        float v = 0.f;
        if (qr >= 0 && qr < 64 && qc >= 0 && qc < 64)
            v = tmp[((size_t)slot * 25 + jj1) * NPT + p] - acc1;
        out[((size_t)(slot + bofs) * 89 + 64 + jj1) * NPT + p] = v;
    }
}

extern "C" void kernel_launch(void* const* d_in, const int* in_sizes, int n_in,
                              void* d_out, int out_size, void* d_ws, size_t ws_size,
                              hipStream_t stream) {
    (void)in_sizes; (void)n_in; (void)out_size;
    const float* x  = (const float*)d_in[0];
    const float* y  = (const float*)d_in[1];
    const float* pw = (const float*)d_in[2];
    const float* pb = (const float*)d_in[3];
    float* out = (float*)d_out;
    float* ws  = (float*)d_ws;

    // per-slot float counts
    const size_t SZ_A   = (size_t)NPT * NPT;        // 16.8M
    const size_t SZ_B   = (size_t)NPT * LDB;        // 17.0M
    const size_t SZ_IL  = (size_t)NKB * NB * NB;    // 262K
    const size_t SZ_N   = NPT;
    const size_t SZ_T   = (size_t)25 * NPT;
    const size_t perSlot = SZ_A + SZ_B + SZ_IL + 2 * SZ_N + SZ_T;

    int nbat;   // slots processed concurrently
    int passes; // sequential passes
    if (ws_size >= 2 * perSlot * sizeof(float)) { nbat = 2; passes = 1; }
    else if (ws_size >= perSlot * sizeof(float)) { nbat = 1; passes = 2; }
    else { return; }  // workspace too small: produce clean absmax failure as diagnostic

    float* Amat = ws;
    float* Brhs = Amat + (size_t)nbat * SZ_A;
    float* invL = Brhs + (size_t)nbat * SZ_B;
    float* nx   = invL + (size_t)nbat * SZ_IL;
    float* ny   = nx + (size_t)nbat * SZ_N;
    float* tmp  = ny + (size_t)nbat * SZ_N;

    for (int pass = 0; pass < passes; ++pass) {
        int bofs = pass * nbat;

        norms_kernel<<<dim3(16, nbat), 256, 0, stream>>>(x, nx, bofs);
        norms_kernel<<<dim3(16, nbat), 256, 0, stream>>>(y, ny, bofs);

        // A = K_yy + sigma*I
        cosgram_kernel<<<dim3(64, 64, nbat), 256, 0, stream>>>(y, y, ny, ny, Amat, NPT,
                                                               (size_t)NPT * NPT, 1, bofs);
        // Brhs[:, 0:4096] = K_yx
        cosgram_kernel<<<dim3(64, 64, nbat), 256, 0, stream>>>(y, x, ny, nx, Brhs, LDB,
                                                               (size_t)NPT * LDB, 0, bofs);
        // Brhs[:, 4096:4160] = ff
        features_kernel<<<dim3(1024, nbat), 256, 0, stream>>>(pw, pb, Brhs);

        // blocked cholesky: A = L L^T (lower), with per-panel inv(L_kk) saved
        for (int kb = 0; kb < NKB; ++kb) {
            potf2_kernel<<<dim3(1, 1, nbat), 256, 0, stream>>>(Amat, invL, kb);
            int nrows = NPT - (kb + 1) * NB;
            if (nrows > 0) {
                trsm_panel_kernel<<<dim3(nrows / 64, 1, nbat), 256, 0, stream>>>(Amat, invL, kb);
                int nt = nrows / 64;
                syrk_kernel<<<dim3(nt, nt, nbat), 256, 0, stream>>>(Amat, kb);
            }
        }

        // blocked forward substitution: L U = [K_xy^T | ff]
        for (int kb = 0; kb < NKB; ++kb) {
            if (kb > 0)
                solve_gemm_kernel<<<dim3(65, 1, nbat), 256, 0, stream>>>(Amat, Brhs, kb);
            trsm_apply_kernel<<<dim3(65, 1, nbat), 256, 0, stream>>>(Brhs, invL, kb);
        }

        // mu = U^T V  -> out channels 0..63
        mu_kernel<<<dim3(64, 1, nbat), 256, 0, stream>>>(Brhs, out, bofs);

        // local covariance -> out channels 64..88
        kxx_local_kernel<<<dim3(4, 64, nbat), 256, 0, stream>>>(x, nx, tmp, bofs);
        cov_local_kernel<<<dim3(4, 64, nbat), 256, 0, stream>>>(Brhs, tmp, out, bofs);
    }
}

// Round 3
// 37656.921 us; speedup vs baseline: 1.4375x; 1.4375x over previous
//
#include <hip/hip_runtime.h>
#include <math.h>

#define NPT 4096      // points per image (64x64)
#define CCH 512       // channels
#define NB 64         // cholesky panel size
#define NKB 64        // NPT / NB
#define LDB 4160      // RHS leading dim = NPT + 64 feature cols
#define SIGF 0.1f
#define CEPS 1e-6f
#define PI8 25.132741228718345f   // 8*pi

typedef __attribute__((ext_vector_type(8))) short bf16x8;
typedef __attribute__((ext_vector_type(4))) float f32x4;
typedef unsigned short ushort_t;

__device__ inline ushort_t f2bf_rne(float x) {
    unsigned u = __float_as_uint(x);
    unsigned r = u + 0x7FFFu + ((u >> 16) & 1u);
    return (ushort_t)(r >> 16);
}
__device__ inline float bf2f(ushort_t h) { return __uint_as_float(((unsigned)h) << 16); }

// ---------------- norms: nrm[slot][p] = ||X[slot+bofs,:,p]|| ----------------
__global__ __launch_bounds__(256) void norms_kernel(const float* __restrict__ X,
                                                    float* __restrict__ nrm, int bofs) {
    int slot = blockIdx.y;
    int p = blockIdx.x * 256 + threadIdx.x;
    const float* Xb = X + (size_t)(slot + bofs) * CCH * NPT;
    float s = 0.f;
    #pragma unroll 8
    for (int ch = 0; ch < CCH; ++ch) {
        float v = Xb[(size_t)ch * NPT + p];
        s += v * v;
    }
    nrm[slot * NPT + p] = sqrtf(s);
}

// ---------------- split: X[b][ch][pt] f32 -> Hi/Lo [slot][pt][ch] bf16 ----------------
__global__ __launch_bounds__(256) void split_kernel(const float* __restrict__ X,
                                                    ushort_t* __restrict__ Hi,
                                                    ushort_t* __restrict__ Lo,
                                                    size_t slotStrideUS, int bofs) {
    int slot = blockIdx.z;
    int ch0 = blockIdx.x * 64, pt0 = blockIdx.y * 64;
    const float* Xb = X + (size_t)(slot + bofs) * CCH * NPT;
    ushort_t* Hb = Hi + (size_t)slot * slotStrideUS;
    ushort_t* Lb = Lo + (size_t)slot * slotStrideUS;
    __shared__ float ls[64][65];
    int tid = threadIdx.x;
    for (int t = tid; t < 4096; t += 256) {
        int chl = t >> 6, ptl = t & 63;
        ls[chl][ptl] = Xb[(size_t)(ch0 + chl) * NPT + pt0 + ptl];
    }
    __syncthreads();
    for (int t = tid; t < 4096; t += 256) {
        int ptl = t >> 6, chl = t & 63;
        float v = ls[chl][ptl];
        ushort_t h = f2bf_rne(v);
        float lo = v - bf2f(h);
        Hb[(size_t)(pt0 + ptl) * CCH + ch0 + chl] = h;
        Lb[(size_t)(pt0 + ptl) * CCH + ch0 + chl] = f2bf_rne(lo);
    }
}

// ------------- cosgram via MFMA split-bf16: C[m,n] = exp(cos(m,n) - 1) -------------
// A-side rows from (Ahi,Alo), B-side cols from (Bhi,Blo), all [pt][ch] bf16.
__global__ __launch_bounds__(256) void cosgram_mfma_kernel(
    const ushort_t* __restrict__ Ahi, const ushort_t* __restrict__ Alo,
    const ushort_t* __restrict__ Bhi, const ushort_t* __restrict__ Blo,
    size_t slotStrideUS,
    const float* __restrict__ nA, const float* __restrict__ nB,
    float* __restrict__ Cm, int ldc, size_t cStride, int addDiag)
{
    int slot = blockIdx.z;
    const ushort_t* pAh = Ahi + (size_t)slot * slotStrideUS;
    const ushort_t* pAl = Alo + (size_t)slot * slotStrideUS;
    const ushort_t* pBh = Bhi + (size_t)slot * slotStrideUS;
    const ushort_t* pBl = Blo + (size_t)slot * slotStrideUS;
    const float* nAb = nA + slot * NPT;
    const float* nBb = nB + slot * NPT;
    float* Cb = Cm + (size_t)slot * cStride;
    int bm = blockIdx.y * 128, bn = blockIdx.x * 128;

    __shared__ __align__(16) ushort_t Ah[128][40];
    __shared__ __align__(16) ushort_t Al[128][40];
    __shared__ __align__(16) ushort_t Bh[128][40];
    __shared__ __align__(16) ushort_t Bl[128][40];

    int tid = threadIdx.x;
    int lane = tid & 63, wid = tid >> 6;
    int wr = wid >> 1, wc = wid & 1;

    f32x4 acc[4][4];
    #pragma unroll
    for (int i = 0; i < 4; ++i)
        #pragma unroll
        for (int j = 0; j < 4; ++j) acc[i][j] = (f32x4){0.f, 0.f, 0.f, 0.f};

    // staging assignment: arr = tid>>6, per iter: row = it*16 + (lane>>2), c4 = lane&3
    int arr = tid >> 6;
    int srow = lane >> 2, sc4 = lane & 3;
    const ushort_t* src = (arr == 0) ? pAh : (arr == 1) ? pAl : (arr == 2) ? pBh : pBl;
    int pbase = (arr < 2) ? bm : bn;
    ushort_t* dst = (arr == 0) ? &Ah[0][0] : (arr == 1) ? &Al[0][0] : (arr == 2) ? &Bh[0][0] : &Bl[0][0];

    for (int k0 = 0; k0 < CCH; k0 += 32) {
        #pragma unroll
        for (int it = 0; it < 8; ++it) {
            int row = it * 16 + srow;
            const ushort_t* g = src + (size_t)(pbase + row) * CCH + k0 + sc4 * 8;
            bf16x8 v = *(const bf16x8*)g;
            *(bf16x8*)(dst + row * 40 + sc4 * 8) = v;
        }
        __syncthreads();
        bf16x8 afh[4], afl[4], bfh[4], bfl[4];
        int kcol = (lane >> 4) * 8;
        #pragma unroll
        for (int mi = 0; mi < 4; ++mi) {
            int r = wr * 64 + mi * 16 + (lane & 15);
            afh[mi] = *(const bf16x8*)&Ah[r][kcol];
            afl[mi] = *(const bf16x8*)&Al[r][kcol];
        }
        #pragma unroll
        for (int nj = 0; nj < 4; ++nj) {
            int r = wc * 64 + nj * 16 + (lane & 15);
            bfh[nj] = *(const bf16x8*)&Bh[r][kcol];
            bfl[nj] = *(const bf16x8*)&Bl[r][kcol];
        }
        #pragma unroll
        for (int mi = 0; mi < 4; ++mi)
            #pragma unroll
            for (int nj = 0; nj < 4; ++nj) {
                acc[mi][nj] = __builtin_amdgcn_mfma_f32_16x16x32_bf16(afh[mi], bfh[nj], acc[mi][nj], 0, 0, 0);
                acc[mi][nj] = __builtin_amdgcn_mfma_f32_16x16x32_bf16(afh[mi], bfl[nj], acc[mi][nj], 0, 0, 0);
                acc[mi][nj] = __builtin_amdgcn_mfma_f32_16x16x32_bf16(afl[mi], bfh[nj], acc[mi][nj], 0, 0, 0);
            }
        __syncthreads();
    }

    // epilogue: C/D layout: col = lane&15, row = (lane>>4)*4 + q   [m89 verified]
    #pragma unroll
    for (int nj = 0; nj < 4; ++nj) {
        int col = bn + wc * 64 + nj * 16 + (lane & 15);
        float nbv = nBb[col];
        #pragma unroll
        for (int mi = 0; mi < 4; ++mi) {
            f32x4 a = acc[mi][nj];
            #pragma unroll
            for (int q = 0; q < 4; ++q) {
                int row = bm + wr * 64 + mi * 16 + (lane >> 4) * 4 + q;
                float den = nAb[row] * nbv + CEPS;
                float v = expf(a[q] / den - 1.0f);
                if (addDiag && row == col) v += SIGF;
                Cb[(size_t)row * ldc + col] = v;
            }
        }
    }
}

// ------------- cosgram (f32 fallback for small ws) -------------
__global__ __launch_bounds__(256) void cosgram_kernel(
    const float* __restrict__ A, const float* __restrict__ B,
    const float* __restrict__ nA, const float* __restrict__ nB,
    float* __restrict__ Cm, int ldc, size_t cBatchStride, int addDiag, int bofs)
{
    int slot = blockIdx.z;
    const float* Ab = A + (size_t)(slot + bofs) * CCH * NPT;
    const float* Bb = B + (size_t)(slot + bofs) * CCH * NPT;
    const float* nAb = nA + slot * NPT;
    const float* nBb = nB + slot * NPT;
    float* Cb = Cm + (size_t)slot * cBatchStride;
    int bm = blockIdx.y * 64, bn = blockIdx.x * 64;
    __shared__ float As[16][64];
    __shared__ float Bs[16][64];
    float acc[4][4] = {};
    int tid = threadIdx.x, tx = tid & 15, ty = tid >> 4;
    int lm = tid & 63, lk = tid >> 6;
    for (int k0 = 0; k0 < CCH; k0 += 16) {
        #pragma unroll
        for (int r = 0; r < 4; ++r) {
            As[lk + r * 4][lm] = Ab[(size_t)(k0 + lk + r * 4) * NPT + bm + lm];
            Bs[lk + r * 4][lm] = Bb[(size_t)(k0 + lk + r * 4) * NPT + bn + lm];
        }
        __syncthreads();
        #pragma unroll
        for (int kk = 0; kk < 16; ++kk) {
            float av[4], bv[4];
            #pragma unroll
            for (int i = 0; i < 4; ++i) { av[i] = As[kk][ty * 4 + i]; bv[i] = Bs[kk][tx * 4 + i]; }
            #pragma unroll
            for (int i = 0; i < 4; ++i)
                #pragma unroll
                for (int j = 0; j < 4; ++j) acc[i][j] += av[i] * bv[j];
        }
        __syncthreads();
    }
    float na[4], nb_[4];
    #pragma unroll
    for (int i = 0; i < 4; ++i) { na[i] = nAb[bm + ty * 4 + i]; nb_[i] = nBb[bn + tx * 4 + i]; }
    #pragma unroll
    for (int i = 0; i < 4; ++i)
        #pragma unroll
        for (int j = 0; j < 4; ++j) {
            int m = bm + ty * 4 + i, n = bn + tx * 4 + j;
            float v = expf(acc[i][j] / (na[i] * nb_[j] + CEPS) - 1.0f);
            if (addDiag && m == n) v += SIGF;
            Cb[(size_t)m * ldc + n] = v;
        }
}

// ------------- features -------------
__global__ __launch_bounds__(256) void features_kernel(const float* __restrict__ pw,
                                                       const float* __restrict__ pb,
                                                       float* __restrict__ Brhs) {
    int slot = blockIdx.y;
    int g = blockIdx.x * 256 + threadIdx.x;
    int q = g >> 6, dd = g & 63;
    int hh = q >> 6, ww = q & 63;
    float gy = -1.0f + (2 * hh + 1) / 64.0f;
    float gx = -1.0f + (2 * ww + 1) / 64.0f;
    float ph = PI8 * (pw[dd * 2 + 0] * gx + pw[dd * 2 + 1] * gy + pb[dd]);
    Brhs[(size_t)slot * NPT * LDB + (size_t)q * LDB + NPT + dd] = cosf(ph);
}

// ------------- potf2 -------------
__global__ __launch_bounds__(256) void potf2_kernel(float* __restrict__ Amat,
                                                    float* __restrict__ invL, int kb) {
    __shared__ float a[NB][NB + 4];
    __shared__ float iv[NB][NB + 4];
    __shared__ float ddiag[NB];
    int slot = blockIdx.z;
    float* Ab = Amat + (size_t)slot * NPT * NPT + ((size_t)kb * NB) * NPT + (size_t)kb * NB;
    int tid = threadIdx.x;
    int tx = tid & 15, ty = tid >> 4;
    for (int t = tid; t < NB * NB; t += 256) {
        int i = t >> 6, j = t & 63;
        a[i][j] = Ab[(size_t)i * NPT + j];
        iv[i][j] = 0.0f;
    }
    __syncthreads();
    for (int j = 0; j < NB; ++j) {
        float ajj = sqrtf(a[j][j]);
        float dinv = 1.0f / ajj;
        if (tid == 0) ddiag[j] = ajj;
        for (int i = j + 1 + tid; i < NB; i += 256) a[i][j] *= dinv;
        for (int c = tid; c <= j; c += 256)
            iv[j][c] = ((c == j ? 1.0f : 0.0f) - iv[j][c]) * dinv;
        __syncthreads();
        for (int i = j + 1 + ty; i < NB; i += 16) {
            float lij = a[i][j];
            for (int jj = j + 1 + tx; jj < NB; jj += 16)
                a[i][jj] -= lij * a[jj][j];
            for (int c = tx; c <= j; c += 16)
                iv[i][c] += lij * iv[j][c];
        }
        __syncthreads();
    }
    float* iL = invL + ((size_t)slot * NKB + kb) * (NB * NB);
    for (int t = tid; t < NB * NB; t += 256) {
        int i = t >> 6, j = t & 63;
        if (j < i)       Ab[(size_t)i * NPT + j] = a[i][j];
        else if (j == i) Ab[(size_t)i * NPT + j] = ddiag[i];
        iL[t] = (j <= i) ? iv[i][j] : 0.0f;
    }
}

// ------------- trsm_panel -------------
__global__ __launch_bounds__(256) void trsm_panel_kernel(float* __restrict__ Amat,
                                                         const float* __restrict__ invL, int kb) {
    int slot = blockIdx.z;
    int r0 = (kb + 1) * NB + blockIdx.x * 64;
    int pcol = kb * NB;
    float* Ab = Amat + (size_t)slot * NPT * NPT;
    const float* iL = invL + ((size_t)slot * NKB + kb) * (NB * NB);
    __shared__ float Ao[64][NB + 1];
    __shared__ float Ls[NB][17];
    float acc[4][4] = {};
    int tid = threadIdx.x, tx = tid & 15, ty = tid >> 4;
    for (int t = tid; t < 64 * NB; t += 256) {
        int i = t >> 6, k = t & 63;
        Ao[i][k] = Ab[(size_t)(r0 + i) * NPT + pcol + k];
    }
    for (int k0 = 0; k0 < NB; k0 += 16) {
        for (int t = tid; t < NB * 16; t += 256) {
            int j = t >> 4, kk = t & 15;
            Ls[j][kk] = iL[j * NB + k0 + kk];
        }
        __syncthreads();
        #pragma unroll
        for (int kk = 0; kk < 16; ++kk) {
            float av[4], lv[4];
            #pragma unroll
            for (int i = 0; i < 4; ++i) { av[i] = Ao[ty * 4 + i][k0 + kk]; lv[i] = Ls[tx * 4 + i][kk]; }
            #pragma unroll
            for (int i = 0; i < 4; ++i)
                #pragma unroll
                for (int j = 0; j < 4; ++j) acc[i][j] += av[i] * lv[j];
        }
        __syncthreads();
    }
    #pragma unroll
    for (int i = 0; i < 4; ++i)
        #pragma unroll
        for (int j = 0; j < 4; ++j)
            Ab[(size_t)(r0 + ty * 4 + i) * NPT + pcol + tx * 4 + j] = acc[i][j];
}

// ------------- syrk -------------
__global__ __launch_bounds__(256) void syrk_kernel(float* __restrict__ Amat, int kb) {
    int bi = blockIdx.y, bj = blockIdx.x;
    if (bj > bi) return;
    int slot = blockIdx.z;
    int off = (kb + 1) * NB;
    int pcol = kb * NB;
    float* Ab = Amat + (size_t)slot * NPT * NPT;
    int i0 = off + bi * 64, j0 = off + bj * 64;
    __shared__ float Pi[64][17];
    __shared__ float Pj[64][17];
    float acc[4][4] = {};
    int tid = threadIdx.x, tx = tid & 15, ty = tid >> 4;
    for (int k0 = 0; k0 < NB; k0 += 16) {
        for (int t = tid; t < 64 * 16; t += 256) {
            int r = t >> 4, kk = t & 15;
            Pi[r][kk] = Ab[(size_t)(i0 + r) * NPT + pcol + k0 + kk];
            Pj[r][kk] = Ab[(size_t)(j0 + r) * NPT + pcol + k0 + kk];
        }
        __syncthreads();
        #pragma unroll
        for (int kk = 0; kk < 16; ++kk) {
            float av[4], bv[4];
            #pragma unroll
            for (int i = 0; i < 4; ++i) { av[i] = Pi[ty * 4 + i][kk]; bv[i] = Pj[tx * 4 + i][kk]; }
            #pragma unroll
            for (int i = 0; i < 4; ++i)
                #pragma unroll
                for (int j = 0; j < 4; ++j) acc[i][j] += av[i] * bv[j];
        }
        __syncthreads();
    }
    #pragma unroll
    for (int i = 0; i < 4; ++i)
        #pragma unroll
        for (int j = 0; j < 4; ++j)
            Ab[(size_t)(i0 + ty * 4 + i) * NPT + j0 + tx * 4 + j] -= acc[i][j];
}

// ------------- solve_gemm: npart==0: Brhs[kb] -= L@U ; npart>0: Part[ks] = partial L@U -------------
__global__ __launch_bounds__(256) void solve_gemm_kernel(const float* __restrict__ Amat,
                                                         float* __restrict__ Brhs,
                                                         float* __restrict__ Part,
                                                         int kb, int npart) {
    int slot = blockIdx.z;
    int ks = blockIdx.y;
    int rb = kb * NB;
    const float* Ab = Amat + (size_t)slot * NPT * NPT;
    float* Bb = Brhs + (size_t)slot * NPT * LDB;
    int n0 = blockIdx.x * 64;
    int K = rb;
    int kbeg = 0, kend = K;
    if (npart > 0) {
        int kseg = K / npart;
        kbeg = ks * kseg;
        kend = (ks == npart - 1) ? K : kbeg + kseg;
    }
    __shared__ float As_[64][17];
    __shared__ float Bs_[16][65];
    float acc[4][4] = {};
    int tid = threadIdx.x, tx = tid & 15, ty = tid >> 4;
    for (int k0 = kbeg; k0 < kend; k0 += 16) {
        for (int t = tid; t < 1024; t += 256) {
            int r = t >> 4, kk = t & 15;
            As_[r][kk] = Ab[(size_t)(rb + r) * NPT + k0 + kk];
        }
        for (int t = tid; t < 1024; t += 256) {
            int kk = t >> 6, c = t & 63;
            Bs_[kk][c] = Bb[(size_t)(k0 + kk) * LDB + n0 + c];
        }
        __syncthreads();
        #pragma unroll
        for (int kk = 0; kk < 16; ++kk) {
            float av[4], bv[4];
            #pragma unroll
            for (int i = 0; i < 4; ++i) { av[i] = As_[ty * 4 + i][kk]; bv[i] = Bs_[kk][tx * 4 + i]; }
            #pragma unroll
            for (int i = 0; i < 4; ++i)
                #pragma unroll
                for (int j = 0; j < 4; ++j) acc[i][j] += av[i] * bv[j];
        }
        __syncthreads();
    }
    if (npart > 0) {
        float* Pp = Part + ((size_t)slot * 2 + ks) * (size_t)NB * LDB;
        #pragma unroll
        for (int i = 0; i < 4; ++i)
            #pragma unroll
            for (int j = 0; j < 4; ++j)
                Pp[(size_t)(ty * 4 + i) * LDB + n0 + tx * 4 + j] = acc[i][j];
    } else {
        #pragma unroll
        for (int i = 0; i < 4; ++i)
            #pragma unroll
            for (int j = 0; j < 4; ++j)
                Bb[(size_t)(rb + ty * 4 + i) * LDB + n0 + tx * 4 + j] -= acc[i][j];
    }
}

// ------------- trsm_apply (subtracts npart partials first) -------------
__global__ __launch_bounds__(256) void trsm_apply_kernel(float* __restrict__ Brhs,
                                                         const float* __restrict__ invL,
                                                         const float* __restrict__ Part,
                                                         int kb, int npart) {
    int slot = blockIdx.z;
    int rb = kb * NB;
    float* Bb = Brhs + (size_t)slot * NPT * LDB;
    const float* iL = invL + ((size_t)slot * NKB + kb) * (NB * NB);
    int n0 = blockIdx.x * 64;
    __shared__ float Ts[NB][65];
    __shared__ float Ls[NB][33];
    float acc[4][4] = {};
    int tid = threadIdx.x, tx = tid & 15, ty = tid >> 4;
    for (int t = tid; t < NB * 64; t += 256) {
        int r = t >> 6, c = t & 63;
        float v = Bb[(size_t)(rb + r) * LDB + n0 + c];
        if (npart > 0) v -= Part[((size_t)slot * 2 + 0) * (size_t)NB * LDB + (size_t)r * LDB + n0 + c];
        if (npart > 1) v -= Part[((size_t)slot * 2 + 1) * (size_t)NB * LDB + (size_t)r * LDB + n0 + c];
        Ts[r][c] = v;
    }
    for (int k0 = 0; k0 < NB; k0 += 32) {
        for (int t = tid; t < NB * 32; t += 256) {
            int r = t >> 5, kk = t & 31;
            Ls[r][kk] = iL[r * NB + k0 + kk];
        }
        __syncthreads();
        #pragma unroll
        for (int kk = 0; kk < 32; ++kk) {
            float tv[4], lv[4];
            #pragma unroll
            for (int i = 0; i < 4; ++i) { tv[i] = Ts[k0 + kk][tx * 4 + i]; lv[i] = Ls[ty * 4 + i][kk]; }
            #pragma unroll
            for (int i = 0; i < 4; ++i)
                #pragma unroll
                for (int j = 0; j < 4; ++j) acc[i][j] += lv[i] * tv[j];
        }
        __syncthreads();
    }
    #pragma unroll
    for (int i = 0; i < 4; ++i)
        #pragma unroll
        for (int j = 0; j < 4; ++j)
            Bb[(size_t)(rb + ty * 4 + i) * LDB + n0 + tx * 4 + j] = acc[i][j];
}

// ------------- mu -------------
__global__ __launch_bounds__(256) void mu_kernel(const float* __restrict__ Brhs,
                                                 float* __restrict__ out, int bofs) {
    int slot = blockIdx.z;
    const float* Bb = Brhs + (size_t)slot * NPT * LDB;
    int p0 = blockIdx.x * 64;
    __shared__ float Us[16][65];
    __shared__ float Vs[16][65];
    float acc[4][4] = {};
    int tid = threadIdx.x, tx = tid & 15, ty = tid >> 4;
    for (int q0 = 0; q0 < NPT; q0 += 16) {
        for (int t = tid; t < 1024; t += 256) {
            int kk = t >> 6, c = t & 63;
            Us[kk][c] = Bb[(size_t)(q0 + kk) * LDB + p0 + c];
            Vs[kk][c] = Bb[(size_t)(q0 + kk) * LDB + NPT + c];
        }
        __syncthreads();
        #pragma unroll
        for (int kk = 0; kk < 16; ++kk) {
            float uv[4], vv[4];
            #pragma unroll
            for (int i = 0; i < 4; ++i) { uv[i] = Us[kk][ty * 4 + i]; vv[i] = Vs[kk][tx * 4 + i]; }
            #pragma unroll
            for (int i = 0; i < 4; ++i)
                #pragma unroll
                for (int j = 0; j < 4; ++j) acc[i][j] += uv[i] * vv[j];
        }
        __syncthreads();
    }
    #pragma unroll
    for (int i = 0; i < 4; ++i)
        #pragma unroll
        for (int j = 0; j < 4; ++j)
            out[((size_t)(slot + bofs) * 89 + tx * 4 + j) * NPT + p0 + ty * 4 + i] = acc[i][j];
}

// ------------- kxx_local -------------
__global__ __launch_bounds__(256) void kxx_local_kernel(const float* __restrict__ X,
                                                        const float* __restrict__ nx,
                                                        float* __restrict__ tmp, int bofs) {
    int slot = blockIdx.z;
    int r = blockIdx.y;
    int c0 = blockIdx.x * 16;
    const float* Xb = X + (size_t)(slot + bofs) * CCH * NPT;
    const float* nxb = nx + slot * NPT;
    __shared__ float Xs[32][104];
    int tid = threadIdx.x;
    int t0 = tid, t1 = tid + 256;
    int pl0 = t0 / 25, jj0 = t0 % 25;
    int pl1 = t1 / 25, jj1 = t1 % 25;
    int pidx0 = 40 + pl0 + 2;
    int jidx0 = (jj0 / 5) * 20 + pl0 + (jj0 % 5);
    int pidx1 = 40 + pl1 + 2;
    int jidx1 = (jj1 / 5) * 20 + pl1 + (jj1 % 5);
    float acc0 = 0.f, acc1 = 0.f;
    for (int ch0 = 0; ch0 < CCH; ch0 += 32) {
        for (int t = tid; t < 32 * 100; t += 256) {
            int ch = t / 100, i = t % 100;
            int s = i / 20, cc = i % 20;
            int gr = r + s - 2, gc = c0 - 2 + cc;
            float v = 0.f;
            if (gr >= 0 && gr < 64 && gc >= 0 && gc < 64)
                v = Xb[(size_t)(ch0 + ch) * NPT + gr * 64 + gc];
            Xs[ch][i] = v;
        }
        __syncthreads();
        #pragma unroll 8
        for (int kk = 0; kk < 32; ++kk) {
            acc0 += Xs[kk][pidx0] * Xs[kk][jidx0];
            if (t1 < 400) acc1 += Xs[kk][pidx1] * Xs[kk][jidx1];
        }
        __syncthreads();
    }
    {
        int p = r * 64 + c0 + pl0;
        int qr = r + jj0 / 5 - 2, qc = c0 + pl0 + jj0 % 5 - 2;
        float v = 0.f;
        if (qr >= 0 && qr < 64 && qc >= 0 && qc < 64) {
            int q = qr * 64 + qc;
            v = expf(acc0 / (nxb[p] * nxb[q] + CEPS) - 1.0f);
        }
        tmp[((size_t)slot * 25 + jj0) * NPT + p] = v;
    }
    if (t1 < 400) {
        int p = r * 64 + c0 + pl1;
        int qr = r + jj1 / 5 - 2, qc = c0 + pl1 + jj1 % 5 - 2;
        float v = 0.f;
        if (qr >= 0 && qr < 64 && qc >= 0 && qc < 64) {
            int q = qr * 64 + qc;
            v = expf(acc1 / (nxb[p] * nxb[q] + CEPS) - 1.0f);
        }
        tmp[((size_t)slot * 25 + jj1) * NPT + p] = v;
    }
}

// ------------- cov_local -------------
__global__ __launch_bounds__(256) void cov_local_kernel(const float* __restrict__ Brhs,
                                                        const float* __restrict__ tmp,
                                                        float* __restrict__ out, int bofs) {
    int slot = blockIdx.z;
    int r = blockIdx.y;
    int c0 = blockIdx.x * 16;
    const float* Ub = Brhs + (size_t)slot * NPT * LDB;
    __shared__ float Us[64][104];
    int tid = threadIdx.x;
    int t0 = tid, t1 = tid + 256;
    int pl0 = t0 / 25, jj0 = t0 % 25;
    int pl1 = t1 / 25, jj1 = t1 % 25;
    int pidx0 = 40 + pl0 + 2;
    int jidx0 = (jj0 / 5) * 20 + pl0 + (jj0 % 5);
    int pidx1 = 40 + pl1 + 2;
    int jidx1 = (jj1 / 5) * 20 + pl1 + (jj1 % 5);
    float acc0 = 0.f, acc1 = 0.f;
    for (int q0 = 0; q0 < NPT; q0 += 64) {
        for (int t = tid; t < 64 * 100; t += 256) {
            int qq = t / 100, i = t % 100;
            int s = i / 20, cc = i % 20;
            int gr = r + s - 2, gc = c0 - 2 + cc;
            float v = 0.f;
            if (gr >= 0 && gr < 64 && gc >= 0 && gc < 64)
                v = Ub[(size_t)(q0 + qq) * LDB + gr * 64 + gc];
            Us[qq][i] = v;
        }
        __syncthreads();
        #pragma unroll 8
        for (int kk = 0; kk < 64; ++kk) {
            acc0 += Us[kk][pidx0] * Us[kk][jidx0];
            if (t1 < 400) acc1 += Us[kk][pidx1] * Us[kk][jidx1];
        }
        __syncthreads();
    }
    {
        int p = r * 64 + c0 + pl0;
        int qr = r + jj0 / 5 - 2, qc = c0 + pl0 + jj0 % 5 - 2;
        float v = 0.f;
        if (qr >= 0 && qr < 64 && qc >= 0 && qc < 64)
            v = tmp[((size_t)slot * 25 + jj0) * NPT + p] - acc0;
        out[((size_t)(slot + bofs) * 89 + 64 + jj0) * NPT + p] = v;
    }
    if (t1 < 400) {
        int p = r * 64 + c0 + pl1;
        int qr = r + jj1 / 5 - 2, qc = c0 + pl1 + jj1 % 5 - 2;
        float v = 0.f;
        if (qr >= 0 && qr < 64 && qc >= 0 && qc < 64)
            v = tmp[((size_t)slot * 25 + jj1) * NPT + p] - acc1;
        out[((size_t)(slot + bofs) * 89 + 64 + jj1) * NPT + p] = v;
    }
}

extern "C" void kernel_launch(void* const* d_in, const int* in_sizes, int n_in,
                              void* d_out, int out_size, void* d_ws, size_t ws_size,
                              hipStream_t stream) {
    (void)in_sizes; (void)n_in; (void)out_size;
    const float* x  = (const float*)d_in[0];
    const float* y  = (const float*)d_in[1];
    const float* pw = (const float*)d_in[2];
    const float* pb = (const float*)d_in[3];
    float* out = (float*)d_out;
    float* ws  = (float*)d_ws;

    const size_t SZ_A   = (size_t)NPT * NPT;        // 16.78M fl
    const size_t SZ_B   = (size_t)NPT * LDB;        // 17.04M fl
    const size_t SZ_IL  = (size_t)NKB * NB * NB;    // 262K fl
    const size_t SZ_N   = NPT;
    const size_t SZ_T   = (size_t)25 * NPT;         // 102K fl
    const size_t SZ_SPL = (size_t)4 * NPT * CCH / 2;  // 4 bf16 arrays as float units: 4.19M fl
    const size_t SPL_US = (size_t)NPT * CCH;          // per-array ushorts per slot
    const size_t PART_FL = (size_t)2 * NB * LDB;      // 532K fl per slot

    const size_t perSlotM = SZ_A + SZ_B + SZ_IL + 2 * SZ_N + SZ_SPL;   // mfma path
    const size_t perSlotC = SZ_A + SZ_B + SZ_IL + 2 * SZ_N + SZ_T;     // fallback

    int nbat, passes, useMfma;
    if      (ws_size >= 2 * perSlotM * sizeof(float)) { nbat = 2; passes = 1; useMfma = 1; }
    else if (ws_size >= perSlotM * sizeof(float))     { nbat = 1; passes = 2; useMfma = 1; }
    else if (ws_size >= perSlotC * sizeof(float))     { nbat = 1; passes = 2; useMfma = 0; }
    else return;

    const size_t perSlot = useMfma ? perSlotM : perSlotC;
    float* Amat = ws;
    float* Brhs = Amat + (size_t)nbat * SZ_A;
    float* invL = Brhs + (size_t)nbat * SZ_B;
    float* nx   = invL + (size_t)nbat * SZ_IL;
    float* ny   = nx + (size_t)nbat * SZ_N;
    float* SplU = ny + (size_t)nbat * SZ_N;           // mfma: splits / parts / tmp ; fallback: tmp
    (void)perSlot;

    // mfma-path carving inside SplU (per slot stride = SZ_SPL floats):
    ushort_t* xs_hi = (ushort_t*)SplU;
    ushort_t* xs_lo = xs_hi + SPL_US * (size_t)nbat;  // interleave per-array: [arr][slot][pt][ch]
    ushort_t* ys_hi = xs_lo + SPL_US * (size_t)nbat;
    ushort_t* ys_lo = ys_hi + SPL_US * (size_t)nbat;
    float* Part = SplU;                                // aliases splits (dead by solve phase)
    float* tmpM = SplU + PART_FL * (size_t)nbat;       // after parts
    float* tmpC = SplU;                                // fallback: tmp at SplU

    for (int pass = 0; pass < passes; ++pass) {
        int bofs = pass * nbat;

        norms_kernel<<<dim3(16, nbat), 256, 0, stream>>>(x, nx, bofs);
        norms_kernel<<<dim3(16, nbat), 256, 0, stream>>>(y, ny, bofs);

        if (useMfma) {
            split_kernel<<<dim3(8, 64, nbat), 256, 0, stream>>>(x, xs_hi, xs_lo, SPL_US, bofs);
            split_kernel<<<dim3(8, 64, nbat), 256, 0, stream>>>(y, ys_hi, ys_lo, SPL_US, bofs);
            // A = K_yy + sigma*I
            cosgram_mfma_kernel<<<dim3(32, 32, nbat), 256, 0, stream>>>(
                ys_hi, ys_lo, ys_hi, ys_lo, SPL_US, ny, ny, Amat, NPT, SZ_A, 1);
            // Brhs[:,0:4096] = K_yx
            cosgram_mfma_kernel<<<dim3(32, 32, nbat), 256, 0, stream>>>(
                ys_hi, ys_lo, xs_hi, xs_lo, SPL_US, ny, nx, Brhs, LDB, SZ_B, 0);
        } else {
            cosgram_kernel<<<dim3(64, 64, nbat), 256, 0, stream>>>(y, y, ny, ny, Amat, NPT, SZ_A, 1, bofs);
            cosgram_kernel<<<dim3(64, 64, nbat), 256, 0, stream>>>(y, x, ny, nx, Brhs, LDB, SZ_B, 0, bofs);
        }
        features_kernel<<<dim3(1024, nbat), 256, 0, stream>>>(pw, pb, Brhs);

        // blocked cholesky
        for (int kb = 0; kb < NKB; ++kb) {
            potf2_kernel<<<dim3(1, 1, nbat), 256, 0, stream>>>(Amat, invL, kb);
            int nrows = NPT - (kb + 1) * NB;
            if (nrows > 0) {
                trsm_panel_kernel<<<dim3(nrows / 64, 1, nbat), 256, 0, stream>>>(Amat, invL, kb);
                int nt = nrows / 64;
                syrk_kernel<<<dim3(nt, nt, nbat), 256, 0, stream>>>(Amat, kb);
            }
        }

        // blocked forward substitution
        for (int kb = 0; kb < NKB; ++kb) {
            int npart = useMfma ? ((kb >= 2) ? 2 : (kb == 1 ? 1 : 0)) : 0;
            if (kb > 0)
                solve_gemm_kernel<<<dim3(65, npart > 0 ? npart : 1, nbat), 256, 0, stream>>>(
                    Amat, Brhs, Part, kb, npart);
            trsm_apply_kernel<<<dim3(65, 1, nbat), 256, 0, stream>>>(Brhs, invL, Part, kb, npart);
        }

        float* tmp = useMfma ? tmpM : tmpC;
        mu_kernel<<<dim3(64, 1, nbat), 256, 0, stream>>>(Brhs, out, bofs);
        kxx_local_kernel<<<dim3(4, 64, nbat), 256, 0, stream>>>(x, nx, tmp, bofs);
        cov_local_kernel<<<dim3(4, 64, nbat), 256, 0, stream>>>(Brhs, tmp, out, bofs);
    }
}

// Round 5
// 23321.059 us; speedup vs baseline: 2.3212x; 1.6147x over previous
//
#include <hip/hip_runtime.h>
#include <math.h>

#define NPT 4096      // points per image (64x64)
#define CCH 512       // channels
#define NB 64         // cholesky panel size
#define NKB 64        // NPT / NB
#define LDB 4160      // RHS leading dim = NPT + 64 feature cols
#define SIGF 0.1f
#define CEPS 1e-6f
#define PI8 25.132741228718345f   // 8*pi

typedef __attribute__((ext_vector_type(8))) short bf16x8;
typedef __attribute__((ext_vector_type(4))) float f32x4;
typedef __attribute__((ext_vector_type(4))) unsigned short us4;
typedef unsigned short ushort_t;

__device__ inline ushort_t f2bf_rne(float x) {
    unsigned u = __float_as_uint(x);
    unsigned r = u + 0x7FFFu + ((u >> 16) & 1u);
    return (ushort_t)(r >> 16);
}
__device__ inline float bf2f(ushort_t h) { return __uint_as_float(((unsigned)h) << 16); }

__device__ inline void split4(float4 v, us4& h, us4& l) {
    h[0] = f2bf_rne(v.x); l[0] = f2bf_rne(v.x - bf2f(h[0]));
    h[1] = f2bf_rne(v.y); l[1] = f2bf_rne(v.y - bf2f(h[1]));
    h[2] = f2bf_rne(v.z); l[2] = f2bf_rne(v.z - bf2f(h[2]));
    h[3] = f2bf_rne(v.w); l[3] = f2bf_rne(v.w - bf2f(h[3]));
}

// ---------------- norms ----------------
__global__ __launch_bounds__(256) void norms_kernel(const float* __restrict__ X,
                                                    float* __restrict__ nrm, int bofs) {
    int slot = blockIdx.y;
    int p = blockIdx.x * 256 + threadIdx.x;
    const float* Xb = X + (size_t)(slot + bofs) * CCH * NPT;
    float s = 0.f;
    #pragma unroll 8
    for (int ch = 0; ch < CCH; ++ch) {
        float v = Xb[(size_t)ch * NPT + p];
        s += v * v;
    }
    nrm[slot * NPT + p] = sqrtf(s);
}

// ---------------- split inputs for grams ----------------
__global__ __launch_bounds__(256) void split_kernel(const float* __restrict__ X,
                                                    ushort_t* __restrict__ Hi,
                                                    ushort_t* __restrict__ Lo,
                                                    size_t slotStrideUS, int bofs) {
    int slot = blockIdx.z;
    int ch0 = blockIdx.x * 64, pt0 = blockIdx.y * 64;
    const float* Xb = X + (size_t)(slot + bofs) * CCH * NPT;
    ushort_t* Hb = Hi + (size_t)slot * slotStrideUS;
    ushort_t* Lb = Lo + (size_t)slot * slotStrideUS;
    __shared__ float ls[64][65];
    int tid = threadIdx.x;
    for (int t = tid; t < 4096; t += 256) {
        int chl = t >> 6, ptl = t & 63;
        ls[chl][ptl] = Xb[(size_t)(ch0 + chl) * NPT + pt0 + ptl];
    }
    __syncthreads();
    for (int t = tid; t < 4096; t += 256) {
        int ptl = t >> 6, chl = t & 63;
        float v = ls[chl][ptl];
        ushort_t h = f2bf_rne(v);
        float lo = v - bf2f(h);
        Hb[(size_t)(pt0 + ptl) * CCH + ch0 + chl] = h;
        Lb[(size_t)(pt0 + ptl) * CCH + ch0 + chl] = f2bf_rne(lo);
    }
}

// ------------- cosgram via MFMA split-bf16 -------------
__global__ __launch_bounds__(256) void cosgram_mfma_kernel(
    const ushort_t* __restrict__ Ahi, const ushort_t* __restrict__ Alo,
    const ushort_t* __restrict__ Bhi, const ushort_t* __restrict__ Blo,
    size_t slotStrideUS,
    const float* __restrict__ nA, const float* __restrict__ nB,
    float* __restrict__ Cm, int ldc, size_t cStride, int addDiag)
{
    int slot = blockIdx.z;
    const ushort_t* pAh = Ahi + (size_t)slot * slotStrideUS;
    const ushort_t* pAl = Alo + (size_t)slot * slotStrideUS;
    const ushort_t* pBh = Bhi + (size_t)slot * slotStrideUS;
    const ushort_t* pBl = Blo + (size_t)slot * slotStrideUS;
    const float* nAb = nA + slot * NPT;
    const float* nBb = nB + slot * NPT;
    float* Cb = Cm + (size_t)slot * cStride;
    int bm = blockIdx.y * 128, bn = blockIdx.x * 128;

    __shared__ __align__(16) ushort_t Ah[128][40];
    __shared__ __align__(16) ushort_t Al[128][40];
    __shared__ __align__(16) ushort_t Bh[128][40];
    __shared__ __align__(16) ushort_t Bl[128][40];

    int tid = threadIdx.x;
    int lane = tid & 63, wid = tid >> 6;
    int wr = wid >> 1, wc = wid & 1;

    f32x4 acc[4][4];
    #pragma unroll
    for (int i = 0; i < 4; ++i)
        #pragma unroll
        for (int j = 0; j < 4; ++j) acc[i][j] = (f32x4){0.f, 0.f, 0.f, 0.f};

    int arr = tid >> 6;
    int srow = lane >> 2, sc4 = lane & 3;
    const ushort_t* src = (arr == 0) ? pAh : (arr == 1) ? pAl : (arr == 2) ? pBh : pBl;
    int pbase = (arr < 2) ? bm : bn;
    ushort_t* dst = (arr == 0) ? &Ah[0][0] : (arr == 1) ? &Al[0][0] : (arr == 2) ? &Bh[0][0] : &Bl[0][0];

    for (int k0 = 0; k0 < CCH; k0 += 32) {
        #pragma unroll
        for (int it = 0; it < 8; ++it) {
            int row = it * 16 + srow;
            const ushort_t* g = src + (size_t)(pbase + row) * CCH + k0 + sc4 * 8;
            bf16x8 v = *(const bf16x8*)g;
            *(bf16x8*)(dst + row * 40 + sc4 * 8) = v;
        }
        __syncthreads();
        bf16x8 afh[4], afl[4], bfh[4], bfl[4];
        int kcol = (lane >> 4) * 8;
        #pragma unroll
        for (int mi = 0; mi < 4; ++mi) {
            int r = wr * 64 + mi * 16 + (lane & 15);
            afh[mi] = *(const bf16x8*)&Ah[r][kcol];
            afl[mi] = *(const bf16x8*)&Al[r][kcol];
        }
        #pragma unroll
        for (int nj = 0; nj < 4; ++nj) {
            int r = wc * 64 + nj * 16 + (lane & 15);
            bfh[nj] = *(const bf16x8*)&Bh[r][kcol];
            bfl[nj] = *(const bf16x8*)&Bl[r][kcol];
        }
        #pragma unroll
        for (int mi = 0; mi < 4; ++mi)
            #pragma unroll
            for (int nj = 0; nj < 4; ++nj) {
                acc[mi][nj] = __builtin_amdgcn_mfma_f32_16x16x32_bf16(afh[mi], bfh[nj], acc[mi][nj], 0, 0, 0);
                acc[mi][nj] = __builtin_amdgcn_mfma_f32_16x16x32_bf16(afh[mi], bfl[nj], acc[mi][nj], 0, 0, 0);
                acc[mi][nj] = __builtin_amdgcn_mfma_f32_16x16x32_bf16(afl[mi], bfh[nj], acc[mi][nj], 0, 0, 0);
            }
        __syncthreads();
    }

    #pragma unroll
    for (int nj = 0; nj < 4; ++nj) {
        int col = bn + wc * 64 + nj * 16 + (lane & 15);
        float nbv = nBb[col];
        #pragma unroll
        for (int mi = 0; mi < 4; ++mi) {
            f32x4 a = acc[mi][nj];
            #pragma unroll
            for (int q = 0; q < 4; ++q) {
                int row = bm + wr * 64 + mi * 16 + (lane >> 4) * 4 + q;
                float den = nAb[row] * nbv + CEPS;
                float v = expf(a[q] / den - 1.0f);
                if (addDiag && row == col) v += SIGF;
                Cb[(size_t)row * ldc + col] = v;
            }
        }
    }
}

// ------------- cosgram (f32 fallback) -------------
__global__ __launch_bounds__(256) void cosgram_kernel(
    const float* __restrict__ A, const float* __restrict__ B,
    const float* __restrict__ nA, const float* __restrict__ nB,
    float* __restrict__ Cm, int ldc, size_t cBatchStride, int addDiag, int bofs)
{
    int slot = blockIdx.z;
    const float* Ab = A + (size_t)(slot + bofs) * CCH * NPT;
    const float* Bb = B + (size_t)(slot + bofs) * CCH * NPT;
    const float* nAb = nA + slot * NPT;
    const float* nBb = nB + slot * NPT;
    float* Cb = Cm + (size_t)slot * cBatchStride;
    int bm = blockIdx.y * 64, bn = blockIdx.x * 64;
    __shared__ float As[16][64];
    __shared__ float Bs[16][64];
    float acc[4][4] = {};
    int tid = threadIdx.x, tx = tid & 15, ty = tid >> 4;
    int lm = tid & 63, lk = tid >> 6;
    for (int k0 = 0; k0 < CCH; k0 += 16) {
        #pragma unroll
        for (int r = 0; r < 4; ++r) {
            As[lk + r * 4][lm] = Ab[(size_t)(k0 + lk + r * 4) * NPT + bm + lm];
            Bs[lk + r * 4][lm] = Bb[(size_t)(k0 + lk + r * 4) * NPT + bn + lm];
        }
        __syncthreads();
        #pragma unroll
        for (int kk = 0; kk < 16; ++kk) {
            float av[4], bv[4];
            #pragma unroll
            for (int i = 0; i < 4; ++i) { av[i] = As[kk][ty * 4 + i]; bv[i] = Bs[kk][tx * 4 + i]; }
            #pragma unroll
            for (int i = 0; i < 4; ++i)
                #pragma unroll
                for (int j = 0; j < 4; ++j) acc[i][j] += av[i] * bv[j];
        }
        __syncthreads();
    }
    float na[4], nb_[4];
    #pragma unroll
    for (int i = 0; i < 4; ++i) { na[i] = nAb[bm + ty * 4 + i]; nb_[i] = nBb[bn + tx * 4 + i]; }
    #pragma unroll
    for (int i = 0; i < 4; ++i)
        #pragma unroll
        for (int j = 0; j < 4; ++j) {
            int m = bm + ty * 4 + i, n = bn + tx * 4 + j;
            float v = expf(acc[i][j] / (na[i] * nb_[j] + CEPS) - 1.0f);
            if (addDiag && m == n) v += SIGF;
            Cb[(size_t)m * ldc + n] = v;
        }
}

// ------------- features -------------
__global__ __launch_bounds__(256) void features_kernel(const float* __restrict__ pw,
                                                       const float* __restrict__ pb,
                                                       float* __restrict__ Brhs) {
    int slot = blockIdx.y;
    int g = blockIdx.x * 256 + threadIdx.x;
    int q = g >> 6, dd = g & 63;
    int hh = q >> 6, ww = q & 63;
    float gy = -1.0f + (2 * hh + 1) / 64.0f;
    float gx = -1.0f + (2 * ww + 1) / 64.0f;
    float ph = PI8 * (pw[dd * 2 + 0] * gx + pw[dd * 2 + 1] * gy + pb[dd]);
    Brhs[(size_t)slot * NPT * LDB + (size_t)q * LDB + NPT + dd] = cosf(ph);
}

// ------------- potf2 (standalone, kb arg) -------------
__global__ __launch_bounds__(256) void potf2_kernel(float* __restrict__ Amat,
                                                    float* __restrict__ invL, int kb) {
    __shared__ float a[NB][NB + 4];
    __shared__ float iv[NB][NB + 4];
    __shared__ float ddiag[NB];
    int slot = blockIdx.z;
    float* Ab = Amat + (size_t)slot * NPT * NPT + ((size_t)kb * NB) * NPT + (size_t)kb * NB;
    int tid = threadIdx.x;
    int tx = tid & 15, ty = tid >> 4;
    for (int t = tid; t < NB * NB; t += 256) {
        int i = t >> 6, j = t & 63;
        a[i][j] = Ab[(size_t)i * NPT + j];
        iv[i][j] = 0.0f;
    }
    __syncthreads();
    for (int j = 0; j < NB; ++j) {
        float ajj = sqrtf(a[j][j]);
        float dinv = 1.0f / ajj;
        if (tid == 0) ddiag[j] = ajj;
        for (int i = j + 1 + tid; i < NB; i += 256) a[i][j] *= dinv;
        for (int c = tid; c <= j; c += 256)
            iv[j][c] = ((c == j ? 1.0f : 0.0f) - iv[j][c]) * dinv;
        __syncthreads();
        for (int i = j + 1 + ty; i < NB; i += 16) {
            float lij = a[i][j];
            for (int jj = j + 1 + tx; jj < NB; jj += 16)
                a[i][jj] -= lij * a[jj][j];
            for (int c = tx; c <= j; c += 16)
                iv[i][c] += lij * iv[j][c];
        }
        __syncthreads();
    }
    float* iL = invL + ((size_t)slot * NKB + kb) * (NB * NB);
    for (int t = tid; t < NB * NB; t += 256) {
        int i = t >> 6, j = t & 63;
        if (j < i)       Ab[(size_t)i * NPT + j] = a[i][j];
        else if (j == i) Ab[(size_t)i * NPT + j] = ddiag[i];
        iL[t] = (j <= i) ? iv[i][j] : 0.0f;
    }
}

// ------------- trsm via MFMA split-bf16: panel = panel @ invL^T -------------
__global__ __launch_bounds__(256) void trsm_mfma_kernel(float* __restrict__ Amat,
                                                        const float* __restrict__ invL, int kb) {
    int slot = blockIdx.z;
    int r0 = (kb + 1) * NB + blockIdx.x * 64;
    int pcol = kb * NB;
    float* Ab = Amat + (size_t)slot * NPT * NPT;
    const float* iL = invL + ((size_t)slot * NKB + kb) * (NB * NB);

    // K=64 staging: 64 data cols + 8 pad  (row stride 144 B, 16B-aligned)
    __shared__ __align__(16) ushort_t Aoh[64][72], Aol[64][72];
    __shared__ __align__(16) ushort_t Bh[64][72], Bl[64][72];

    int tid = threadIdx.x, lane = tid & 63, w = tid >> 6;
    int frow = lane & 15, fk = (lane >> 4) << 3;
    f32x4 acc[4];
    #pragma unroll
    for (int j = 0; j < 4; ++j) acc[j] = (f32x4){0, 0, 0, 0};

    for (int e = tid; e < 1024; e += 256) {
        int r = e >> 4, k4 = e & 15;
        us4 h, l;
        float4 v = *(const float4*)&Ab[(size_t)(r0 + r) * NPT + pcol + (k4 << 2)];
        split4(v, h, l);
        *(us4*)&Aoh[r][k4 << 2] = h; *(us4*)&Aol[r][k4 << 2] = l;
        float4 u = *(const float4*)&iL[(r << 6) + (k4 << 2)];
        split4(u, h, l);
        *(us4*)&Bh[r][k4 << 2] = h; *(us4*)&Bl[r][k4 << 2] = l;
    }
    __syncthreads();
    #pragma unroll
    for (int kk0 = 0; kk0 < 64; kk0 += 32) {
        bf16x8 ah = *(const bf16x8*)&Aoh[(w << 4) + frow][kk0 + fk];
        bf16x8 al = *(const bf16x8*)&Aol[(w << 4) + frow][kk0 + fk];
        #pragma unroll
        for (int nj = 0; nj < 4; ++nj) {
            bf16x8 bh = *(const bf16x8*)&Bh[(nj << 4) + frow][kk0 + fk];
            bf16x8 bl = *(const bf16x8*)&Bl[(nj << 4) + frow][kk0 + fk];
            acc[nj] = __builtin_amdgcn_mfma_f32_16x16x32_bf16(ah, bh, acc[nj], 0, 0, 0);
            acc[nj] = __builtin_amdgcn_mfma_f32_16x16x32_bf16(ah, bl, acc[nj], 0, 0, 0);
            acc[nj] = __builtin_amdgcn_mfma_f32_16x16x32_bf16(al, bh, acc[nj], 0, 0, 0);
        }
    }
    #pragma unroll
    for (int nj = 0; nj < 4; ++nj)
        #pragma unroll
        for (int q = 0; q < 4; ++q) {
            int row = r0 + (w << 4) + ((lane >> 4) << 2) + q;
            Ab[(size_t)row * NPT + pcol + (nj << 4) + frow] = acc[nj][q];
        }
}

// ------------- syrk via MFMA + fused potf2 of next diag block -------------
__global__ __launch_bounds__(256) void syrk_fact_kernel(float* __restrict__ Amat,
                                                        float* __restrict__ invL, int kb) {
    int bi = blockIdx.y, bj = blockIdx.x;
    if (bj > bi) return;
    int slot = blockIdx.z;
    int off = (kb + 1) * NB;
    int pcol = kb * NB;
    float* Ab = Amat + (size_t)slot * NPT * NPT;
    int i0 = off + bi * 64, j0 = off + bj * 64;

    // 4 x [64][72] ushort tiles (9216 B each); potf2 scratch aliases after panels are dead
    __shared__ __align__(16) char smem[36864];
    ushort_t (*Pih)[72] = (ushort_t(*)[72])(smem);
    ushort_t (*Pil)[72] = (ushort_t(*)[72])(smem + 9216);
    ushort_t (*Pjh)[72] = (ushort_t(*)[72])(smem + 18432);
    ushort_t (*Pjl)[72] = (ushort_t(*)[72])(smem + 27648);
    float (*fa)[68] = (float(*)[68])(smem);
    float (*fiv)[68] = (float(*)[68])(smem + 17408);
    float* fdd = (float*)(smem + 34816);

    int tid = threadIdx.x, lane = tid & 63, w = tid >> 6;
    int frow = lane & 15, fk = (lane >> 4) << 3;
    f32x4 acc[4];
    #pragma unroll
    for (int j = 0; j < 4; ++j) acc[j] = (f32x4){0, 0, 0, 0};

    for (int e = tid; e < 1024; e += 256) {
        int r = e >> 4, k4 = e & 15;
        us4 h, l;
        float4 v = *(const float4*)&Ab[(size_t)(i0 + r) * NPT + pcol + (k4 << 2)];
        split4(v, h, l);
        *(us4*)&Pih[r][k4 << 2] = h; *(us4*)&Pil[r][k4 << 2] = l;
        float4 u = *(const float4*)&Ab[(size_t)(j0 + r) * NPT + pcol + (k4 << 2)];
        split4(u, h, l);
        *(us4*)&Pjh[r][k4 << 2] = h; *(us4*)&Pjl[r][k4 << 2] = l;
    }
    __syncthreads();
    #pragma unroll
    for (int kk0 = 0; kk0 < 64; kk0 += 32) {
        bf16x8 ah = *(const bf16x8*)&Pih[(w << 4) + frow][kk0 + fk];
        bf16x8 al = *(const bf16x8*)&Pil[(w << 4) + frow][kk0 + fk];
        #pragma unroll
        for (int nj = 0; nj < 4; ++nj) {
            bf16x8 bh = *(const bf16x8*)&Pjh[(nj << 4) + frow][kk0 + fk];
            bf16x8 bl = *(const bf16x8*)&Pjl[(nj << 4) + frow][kk0 + fk];
            acc[nj] = __builtin_amdgcn_mfma_f32_16x16x32_bf16(ah, bh, acc[nj], 0, 0, 0);
            acc[nj] = __builtin_amdgcn_mfma_f32_16x16x32_bf16(ah, bl, acc[nj], 0, 0, 0);
            acc[nj] = __builtin_amdgcn_mfma_f32_16x16x32_bf16(al, bh, acc[nj], 0, 0, 0);
        }
    }

    if (!(bi == 0 && bj == 0)) {
        #pragma unroll
        for (int nj = 0; nj < 4; ++nj) {
            int col = j0 + (nj << 4) + frow;
            #pragma unroll
            for (int q = 0; q < 4; ++q) {
                int row = i0 + (w << 4) + ((lane >> 4) << 2) + q;
                size_t idx = (size_t)row * NPT + col;
                Ab[idx] -= acc[nj][q];
            }
        }
        return;
    }

    // fused potf2 of updated diag tile (kb+1)
    __syncthreads();   // panels (aliased by fa/fiv) no longer read
    #pragma unroll
    for (int nj = 0; nj < 4; ++nj) {
        int col = (nj << 4) + frow;
        #pragma unroll
        for (int q = 0; q < 4; ++q) {
            int row = (w << 4) + ((lane >> 4) << 2) + q;
            fa[row][col] = Ab[(size_t)(i0 + row) * NPT + j0 + col] - acc[nj][q];
            fiv[row][col] = 0.0f;
        }
    }
    __syncthreads();
    int tx = tid & 15, ty = tid >> 4;
    for (int j = 0; j < NB; ++j) {
        float ajj = sqrtf(fa[j][j]);
        float dinv = 1.0f / ajj;
        if (tid == 0) fdd[j] = ajj;
        for (int i = j + 1 + tid; i < NB; i += 256) fa[i][j] *= dinv;
        for (int c = tid; c <= j; c += 256)
            fiv[j][c] = ((c == j ? 1.0f : 0.0f) - fiv[j][c]) * dinv;
        __syncthreads();
        for (int i = j + 1 + ty; i < NB; i += 16) {
            float lij = fa[i][j];
            for (int jj = j + 1 + tx; jj < NB; jj += 16)
                fa[i][jj] -= lij * fa[jj][j];
            for (int c = tx; c <= j; c += 16)
                fiv[i][c] += lij * fiv[j][c];
        }
        __syncthreads();
    }
    float* iL = invL + ((size_t)slot * NKB + (kb + 1)) * (NB * NB);
    for (int t = tid; t < NB * NB; t += 256) {
        int i = t >> 6, j = t & 63;
        if (j < i)       Ab[(size_t)(i0 + i) * NPT + j0 + j] = fa[i][j];
        else if (j == i) Ab[(size_t)(i0 + i) * NPT + j0 + j] = fdd[i];
        iL[t] = (j <= i) ? fiv[i][j] : 0.0f;
    }
}

// ------------- fused forward solve: one launch, 130 column-stripe blocks -------------
__global__ __launch_bounds__(256) void solve_fused_kernel(const float* __restrict__ Amat,
                                                          float* __restrict__ Brhs,
                                                          const float* __restrict__ invL) {
    int slot = blockIdx.z;
    int n0 = blockIdx.x * 32;
    const float* Ab = Amat + (size_t)slot * NPT * NPT;
    float* Bb = Brhs + (size_t)slot * NPT * LDB;
    const float* iLbase = invL + (size_t)slot * NKB * (NB * NB);

    __shared__ __align__(16) ushort_t Lh[64][136], Ll[64][136];
    __shared__ __align__(16) ushort_t Uh[32][136], Ul[32][136];
    __shared__ float invLs[64][68];
    __shared__ float Tds[64][36];

    int tid = threadIdx.x, lane = tid & 63, w = tid >> 6;
    int frow = lane & 15, fk = (lane >> 4) << 3;

    for (int kb = 0; kb < NKB; ++kb) {
        int rb = kb * NB;
        f32x4 acc[2];
        acc[0] = (f32x4){0, 0, 0, 0};
        acc[1] = (f32x4){0, 0, 0, 0};
        for (int k0 = 0; k0 < rb; k0 += 128) {
            int kc = rb - k0; if (kc > 128) kc = 128;
            if (kc == 128) {
                for (int e = tid; e < 2048; e += 256) {
                    int r = e >> 5, k4 = e & 31;
                    us4 h, l;
                    float4 v = *(const float4*)&Ab[(size_t)(rb + r) * NPT + k0 + (k4 << 2)];
                    split4(v, h, l);
                    *(us4*)&Lh[r][k4 << 2] = h; *(us4*)&Ll[r][k4 << 2] = l;
                }
            } else {
                for (int e = tid; e < 1024; e += 256) {
                    int r = e >> 4, k4 = e & 15;
                    us4 h, l;
                    float4 v = *(const float4*)&Ab[(size_t)(rb + r) * NPT + k0 + (k4 << 2)];
                    split4(v, h, l);
                    *(us4*)&Lh[r][k4 << 2] = h; *(us4*)&Ll[r][k4 << 2] = l;
                }
            }
            for (int e = tid; e < (kc << 3); e += 256) {
                int kk = e >> 3, c4 = e & 7;
                float4 v = *(const float4*)&Bb[(size_t)(k0 + kk) * LDB + n0 + (c4 << 2)];
                int c = c4 << 2;
                ushort_t h0 = f2bf_rne(v.x); Uh[c][kk] = h0;     Ul[c][kk]     = f2bf_rne(v.x - bf2f(h0));
                ushort_t h1 = f2bf_rne(v.y); Uh[c + 1][kk] = h1; Ul[c + 1][kk] = f2bf_rne(v.y - bf2f(h1));
                ushort_t h2 = f2bf_rne(v.z); Uh[c + 2][kk] = h2; Ul[c + 2][kk] = f2bf_rne(v.z - bf2f(h2));
                ushort_t h3 = f2bf_rne(v.w); Uh[c + 3][kk] = h3; Ul[c + 3][kk] = f2bf_rne(v.w - bf2f(h3));
            }
            __syncthreads();
            for (int kk0 = 0; kk0 < kc; kk0 += 32) {
                bf16x8 ah = *(const bf16x8*)&Lh[(w << 4) + frow][kk0 + fk];
                bf16x8 al = *(const bf16x8*)&Ll[(w << 4) + frow][kk0 + fk];
                #pragma unroll
                for (int s = 0; s < 2; ++s) {
                    bf16x8 bh = *(const bf16x8*)&Uh[(s << 4) + frow][kk0 + fk];
                    bf16x8 bl = *(const bf16x8*)&Ul[(s << 4) + frow][kk0 + fk];
                    acc[s] = __builtin_amdgcn_mfma_f32_16x16x32_bf16(ah, bh, acc[s], 0, 0, 0);
                    acc[s] = __builtin_amdgcn_mfma_f32_16x16x32_bf16(ah, bl, acc[s], 0, 0, 0);
                    acc[s] = __builtin_amdgcn_mfma_f32_16x16x32_bf16(al, bh, acc[s], 0, 0, 0);
                }
            }
            __syncthreads();
        }
        #pragma unroll
        for (int s = 0; s < 2; ++s)
            #pragma unroll
            for (int q = 0; q < 4; ++q)
                Tds[(w << 4) + ((lane >> 4) << 2) + q][(s << 4) + frow] = acc[s][q];
        for (int e = tid; e < 1024; e += 256) {
            int r = e >> 4, k4 = e & 15;
            float4 v = *(const float4*)&iLbase[((size_t)kb << 12) + (r << 6) + (k4 << 2)];
            int k = k4 << 2;
            invLs[r][k] = v.x; invLs[r][k + 1] = v.y; invLs[r][k + 2] = v.z; invLs[r][k + 3] = v.w;
        }
        __syncthreads();
        for (int e = tid; e < 512; e += 256) {
            int r = e >> 3, c4 = e & 7;
            float4 v = *(const float4*)&Bb[(size_t)(rb + r) * LDB + n0 + (c4 << 2)];
            int c = c4 << 2;
            Tds[r][c]     = v.x - Tds[r][c];
            Tds[r][c + 1] = v.y - Tds[r][c + 1];
            Tds[r][c + 2] = v.z - Tds[r][c + 2];
            Tds[r][c + 3] = v.w - Tds[r][c + 3];
        }
        __syncthreads();
        int r8 = tid >> 5, cc = tid & 31;
        #pragma unroll
        for (int i = 0; i < 8; ++i) {
            int row = (i << 3) + r8;
            float s = 0.f;
            #pragma unroll 16
            for (int k = 0; k < 64; ++k) s += invLs[row][k] * Tds[k][cc];
            Bb[(size_t)(rb + row) * LDB + n0 + cc] = s;
        }
        __threadfence_block();
        __syncthreads();
    }
}

// ------------- fallback f32 kernels (trsm/syrk/solve) -------------
__global__ __launch_bounds__(256) void trsm_panel_kernel(float* __restrict__ Amat,
                                                         const float* __restrict__ invL, int kb) {
    int slot = blockIdx.z;
    int r0 = (kb + 1) * NB + blockIdx.x * 64;
    int pcol = kb * NB;
    float* Ab = Amat + (size_t)slot * NPT * NPT;
    const float* iL = invL + ((size_t)slot * NKB + kb) * (NB * NB);
    __shared__ float Ao[64][NB + 1];
    __shared__ float Ls[NB][17];
    float acc[4][4] = {};
    int tid = threadIdx.x, tx = tid & 15, ty = tid >> 4;
    for (int t = tid; t < 64 * NB; t += 256) {
        int i = t >> 6, k = t & 63;
        Ao[i][k] = Ab[(size_t)(r0 + i) * NPT + pcol + k];
    }
    for (int k0 = 0; k0 < NB; k0 += 16) {
        for (int t = tid; t < NB * 16; t += 256) {
            int j = t >> 4, kk = t & 15;
            Ls[j][kk] = iL[j * NB + k0 + kk];
        }
        __syncthreads();
        #pragma unroll
        for (int kk = 0; kk < 16; ++kk) {
            float av[4], lv[4];
            #pragma unroll
            for (int i = 0; i < 4; ++i) { av[i] = Ao[ty * 4 + i][k0 + kk]; lv[i] = Ls[tx * 4 + i][kk]; }
            #pragma unroll
            for (int i = 0; i < 4; ++i)
                #pragma unroll
                for (int j = 0; j < 4; ++j) acc[i][j] += av[i] * lv[j];
        }
        __syncthreads();
    }
    #pragma unroll
    for (int i = 0; i < 4; ++i)
        #pragma unroll
        for (int j = 0; j < 4; ++j)
            Ab[(size_t)(r0 + ty * 4 + i) * NPT + pcol + tx * 4 + j] = acc[i][j];
}

__global__ __launch_bounds__(256) void syrk_kernel(float* __restrict__ Amat, int kb) {
    int bi = blockIdx.y, bj = blockIdx.x;
    if (bj > bi) return;
    int slot = blockIdx.z;
    int off = (kb + 1) * NB;
    int pcol = kb * NB;
    float* Ab = Amat + (size_t)slot * NPT * NPT;
    int i0 = off + bi * 64, j0 = off + bj * 64;
    __shared__ float Pi[64][17];
    __shared__ float Pj[64][17];
    float acc[4][4] = {};
    int tid = threadIdx.x, tx = tid & 15, ty = tid >> 4;
    for (int k0 = 0; k0 < NB; k0 += 16) {
        for (int t = tid; t < 64 * 16; t += 256) {
            int r = t >> 4, kk = t & 15;
            Pi[r][kk] = Ab[(size_t)(i0 + r) * NPT + pcol + k0 + kk];
            Pj[r][kk] = Ab[(size_t)(j0 + r) * NPT + pcol + k0 + kk];
        }
        __syncthreads();
        #pragma unroll
        for (int kk = 0; kk < 16; ++kk) {
            float av[4], bv[4];
            #pragma unroll
            for (int i = 0; i < 4; ++i) { av[i] = Pi[ty * 4 + i][kk]; bv[i] = Pj[tx * 4 + i][kk]; }
            #pragma unroll
            for (int i = 0; i < 4; ++i)
                #pragma unroll
                for (int j = 0; j < 4; ++j) acc[i][j] += av[i] * bv[j];
        }
        __syncthreads();
    }
    #pragma unroll
    for (int i = 0; i < 4; ++i)
        #pragma unroll
        for (int j = 0; j < 4; ++j)
            Ab[(size_t)(i0 + ty * 4 + i) * NPT + j0 + tx * 4 + j] -= acc[i][j];
}

__global__ __launch_bounds__(256) void solve_gemm_kernel(const float* __restrict__ Amat,
                                                         float* __restrict__ Brhs, int kb) {
    int slot = blockIdx.z;
    int rb = kb * NB;
    const float* Ab = Amat + (size_t)slot * NPT * NPT;
    float* Bb = Brhs + (size_t)slot * NPT * LDB;
    int n0 = blockIdx.x * 64;
    int K = rb;
    __shared__ float As_[64][17];
    __shared__ float Bs_[16][65];
    float acc[4][4] = {};
    int tid = threadIdx.x, tx = tid & 15, ty = tid >> 4;
    for (int k0 = 0; k0 < K; k0 += 16) {
        for (int t = tid; t < 1024; t += 256) {
            int r = t >> 4, kk = t & 15;
            As_[r][kk] = Ab[(size_t)(rb + r) * NPT + k0 + kk];
        }
        for (int t = tid; t < 1024; t += 256) {
            int kk = t >> 6, c = t & 63;
            Bs_[kk][c] = Bb[(size_t)(k0 + kk) * LDB + n0 + c];
        }
        __syncthreads();
        #pragma unroll
        for (int kk = 0; kk < 16; ++kk) {
            float av[4], bv[4];
            #pragma unroll
            for (int i = 0; i < 4; ++i) { av[i] = As_[ty * 4 + i][kk]; bv[i] = Bs_[kk][tx * 4 + i]; }
            #pragma unroll
            for (int i = 0; i < 4; ++i)
                #pragma unroll
                for (int j = 0; j < 4; ++j) acc[i][j] += av[i] * bv[j];
        }
        __syncthreads();
    }
    #pragma unroll
    for (int i = 0; i < 4; ++i)
        #pragma unroll
        for (int j = 0; j < 4; ++j)
            Bb[(size_t)(rb + ty * 4 + i) * LDB + n0 + tx * 4 + j] -= acc[i][j];
}

__global__ __launch_bounds__(256) void trsm_apply_kernel(float* __restrict__ Brhs,
                                                         const float* __restrict__ invL, int kb) {
    int slot = blockIdx.z;
    int rb = kb * NB;
    float* Bb = Brhs + (size_t)slot * NPT * LDB;
    const float* iL = invL + ((size_t)slot * NKB + kb) * (NB * NB);
    int n0 = blockIdx.x * 64;
    __shared__ float Ts[NB][65];
    __shared__ float Ls[NB][33];
    float acc[4][4] = {};
    int tid = threadIdx.x, tx = tid & 15, ty = tid >> 4;
    for (int t = tid; t < NB * 64; t += 256) {
        int r = t >> 6, c = t & 63;
        Ts[r][c] = Bb[(size_t)(rb + r) * LDB + n0 + c];
    }
    for (int k0 = 0; k0 < NB; k0 += 32) {
        for (int t = tid; t < NB * 32; t += 256) {
            int r = t >> 5, kk = t & 31;
            Ls[r][kk] = iL[r * NB + k0 + kk];
        }
        __syncthreads();
        #pragma unroll
        for (int kk = 0; kk < 32; ++kk) {
            float tv[4], lv[4];
            #pragma unroll
            for (int i = 0; i < 4; ++i) { tv[i] = Ts[k0 + kk][tx * 4 + i]; lv[i] = Ls[ty * 4 + i][kk]; }
            #pragma unroll
            for (int i = 0; i < 4; ++i)
                #pragma unroll
                for (int j = 0; j < 4; ++j) acc[i][j] += lv[i] * tv[j];
        }
        __syncthreads();
    }
    #pragma unroll
    for (int i = 0; i < 4; ++i)
        #pragma unroll
        for (int j = 0; j < 4; ++j)
            Bb[(size_t)(rb + ty * 4 + i) * LDB + n0 + tx * 4 + j] = acc[i][j];
}

// ------------- mu -------------
__global__ __launch_bounds__(256) void mu_kernel(const float* __restrict__ Brhs,
                                                 float* __restrict__ out, int bofs) {
    int slot = blockIdx.z;
    const float* Bb = Brhs + (size_t)slot * NPT * LDB;
    int p0 = blockIdx.x * 64;
    __shared__ float Us[16][65];
    __shared__ float Vs[16][65];
    float acc[4][4] = {};
    int tid = threadIdx.x, tx = tid & 15, ty = tid >> 4;
    for (int q0 = 0; q0 < NPT; q0 += 16) {
        for (int t = tid; t < 1024; t += 256) {
            int kk = t >> 6, c = t & 63;
            Us[kk][c] = Bb[(size_t)(q0 + kk) * LDB + p0 + c];
            Vs[kk][c] = Bb[(size_t)(q0 + kk) * LDB + NPT + c];
        }
        __syncthreads();
        #pragma unroll
        for (int kk = 0; kk < 16; ++kk) {
            float uv[4], vv[4];
            #pragma unroll
            for (int i = 0; i < 4; ++i) { uv[i] = Us[kk][ty * 4 + i]; vv[i] = Vs[kk][tx * 4 + i]; }
            #pragma unroll
            for (int i = 0; i < 4; ++i)
                #pragma unroll
                for (int j = 0; j < 4; ++j) acc[i][j] += uv[i] * vv[j];
        }
        __syncthreads();
    }
    #pragma unroll
    for (int i = 0; i < 4; ++i)
        #pragma unroll
        for (int j = 0; j < 4; ++j)
            out[((size_t)(slot + bofs) * 89 + tx * 4 + j) * NPT + p0 + ty * 4 + i] = acc[i][j];
}

// ------------- kxx_local -------------
__global__ __launch_bounds__(256) void kxx_local_kernel(const float* __restrict__ X,
                                                        const float* __restrict__ nx,
                                                        float* __restrict__ tmp, int bofs) {
    int slot = blockIdx.z;
    int r = blockIdx.y;
    int c0 = blockIdx.x * 16;
    const float* Xb = X + (size_t)(slot + bofs) * CCH * NPT;
    const float* nxb = nx + slot * NPT;
    __shared__ float Xs[32][104];
    int tid = threadIdx.x;
    int t0 = tid, t1 = tid + 256;
    int pl0 = t0 / 25, jj0 = t0 % 25;
    int pl1 = t1 / 25, jj1 = t1 % 25;
    int pidx0 = 40 + pl0 + 2;
    int jidx0 = (jj0 / 5) * 20 + pl0 + (jj0 % 5);
    int pidx1 = 40 + pl1 + 2;
    int jidx1 = (jj1 / 5) * 20 + pl1 + (jj1 % 5);
    float acc0 = 0.f, acc1 = 0.f;
    for (int ch0 = 0; ch0 < CCH; ch0 += 32) {
        for (int t = tid; t < 32 * 100; t += 256) {
            int ch = t / 100, i = t % 100;
            int s = i / 20, cc = i % 20;
            int gr = r + s - 2, gc = c0 - 2 + cc;
            float v = 0.f;
            if (gr >= 0 && gr < 64 && gc >= 0 && gc < 64)
                v = Xb[(size_t)(ch0 + ch) * NPT + gr * 64 + gc];
            Xs[ch][i] = v;
        }
        __syncthreads();
        #pragma unroll 8
        for (int kk = 0; kk < 32; ++kk) {
            acc0 += Xs[kk][pidx0] * Xs[kk][jidx0];
            if (t1 < 400) acc1 += Xs[kk][pidx1] * Xs[kk][jidx1];
        }
        __syncthreads();
    }
    {
        int p = r * 64 + c0 + pl0;
        int qr = r + jj0 / 5 - 2, qc = c0 + pl0 + jj0 % 5 - 2;
        float v = 0.f;
        if (qr >= 0 && qr < 64 && qc >= 0 && qc < 64) {
            int q = qr * 64 + qc;
            v = expf(acc0 / (nxb[p] * nxb[q] + CEPS) - 1.0f);
        }
        tmp[((size_t)slot * 25 + jj0) * NPT + p] = v;
    }
    if (t1 < 400) {
        int p = r * 64 + c0 + pl1;
        int qr = r + jj1 / 5 - 2, qc = c0 + pl1 + jj1 % 5 - 2;
        float v = 0.f;
        if (qr >= 0 && qr < 64 && qc >= 0 && qc < 64) {
            int q = qr * 64 + qc;
            v = expf(acc1 / (nxb[p] * nxb[q] + CEPS) - 1.0f);
        }
        tmp[((size_t)slot * 25 + jj1) * NPT + p] = v;
    }
}

// ------------- cov_local -------------
__global__ __launch_bounds__(256) void cov_local_kernel(const float* __restrict__ Brhs,
                                                        const float* __restrict__ tmp,
                                                        float* __restrict__ out, int bofs) {
    int slot = blockIdx.z;
    int r = blockIdx.y;
    int c0 = blockIdx.x * 16;
    const float* Ub = Brhs + (size_t)slot * NPT * LDB;
    __shared__ float Us[64][104];
    int tid = threadIdx.x;
    int t0 = tid, t1 = tid + 256;
    int pl0 = t0 / 25, jj0 = t0 % 25;
    int pl1 = t1 / 25, jj1 = t1 % 25;
    int pidx0 = 40 + pl0 + 2;
    int jidx0 = (jj0 / 5) * 20 + pl0 + (jj0 % 5);
    int pidx1 = 40 + pl1 + 2;
    int jidx1 = (jj1 / 5) * 20 + pl1 + (jj1 % 5);
    float acc0 = 0.f, acc1 = 0.f;
    for (int q0 = 0; q0 < NPT; q0 += 64) {
        for (int t = tid; t < 64 * 100; t += 256) {
            int qq = t / 100, i = t % 100;
            int s = i / 20, cc = i % 20;
            int gr = r + s - 2, gc = c0 - 2 + cc;
            float v = 0.f;
            if (gr >= 0 && gr < 64 && gc >= 0 && gc < 64)
                v = Ub[(size_t)(q0 + qq) * LDB + gr * 64 + gc];
            Us[qq][i] = v;
        }
        __syncthreads();
        #pragma unroll 8
        for (int kk = 0; kk < 64; ++kk) {
            acc0 += Us[kk][pidx0] * Us[kk][jidx0];
            if (t1 < 400) acc1 += Us[kk][pidx1] * Us[kk][jidx1];
        }
        __syncthreads();
    }
    {
        int p = r * 64 + c0 + pl0;
        int qr = r + jj0 / 5 - 2, qc = c0 + pl0 + jj0 % 5 - 2;
        float v = 0.f;
        if (qr >= 0 && qr < 64 && qc >= 0 && qc < 64)
            v = tmp[((size_t)slot * 25 + jj0) * NPT + p] - acc0;
        out[((size_t)(slot + bofs) * 89 + 64 + jj0) * NPT + p] = v;
    }
    if (t1 < 400) {
        int p = r * 64 + c0 + pl1;
        int qr = r + jj1 / 5 - 2, qc = c0 + pl1 + jj1 % 5 - 2;
        float v = 0.f;
        if (qr >= 0 && qr < 64 && qc >= 0 && qc < 64)
            v = tmp[((size_t)slot * 25 + jj1) * NPT + p] - acc1;
        out[((size_t)(slot + bofs) * 89 + 64 + jj1) * NPT + p] = v;
    }
}

extern "C" void kernel_launch(void* const* d_in, const int* in_sizes, int n_in,
                              void* d_out, int out_size, void* d_ws, size_t ws_size,
                              hipStream_t stream) {
    (void)in_sizes; (void)n_in; (void)out_size;
    const float* x  = (const float*)d_in[0];
    const float* y  = (const float*)d_in[1];
    const float* pw = (const float*)d_in[2];
    const float* pb = (const float*)d_in[3];
    float* out = (float*)d_out;
    float* ws  = (float*)d_ws;

    const size_t SZ_A   = (size_t)NPT * NPT;
    const size_t SZ_B   = (size_t)NPT * LDB;
    const size_t SZ_IL  = (size_t)NKB * NB * NB;
    const size_t SZ_N   = NPT;
    const size_t SZ_T   = (size_t)25 * NPT;
    const size_t SZ_SPL = (size_t)4 * NPT * CCH / 2;  // 4 bf16 arrays in float units
    const size_t SPL_US = (size_t)NPT * CCH;

    const size_t perSlotM = SZ_A + SZ_B + SZ_IL + 2 * SZ_N + SZ_SPL;
    const size_t perSlotC = SZ_A + SZ_B + SZ_IL + 2 * SZ_N + SZ_T;

    int nbat, passes, useMfma;
    if      (ws_size >= 2 * perSlotM * sizeof(float)) { nbat = 2; passes = 1; useMfma = 1; }
    else if (ws_size >= perSlotM * sizeof(float))     { nbat = 1; passes = 2; useMfma = 1; }
    else if (ws_size >= perSlotC * sizeof(float))     { nbat = 1; passes = 2; useMfma = 0; }
    else return;

    float* Amat = ws;
    float* Brhs = Amat + (size_t)nbat * SZ_A;
    float* invL = Brhs + (size_t)nbat * SZ_B;
    float* nx   = invL + (size_t)nbat * SZ_IL;
    float* ny   = nx + (size_t)nbat * SZ_N;
    float* SplU = ny + (size_t)nbat * SZ_N;

    ushort_t* xs_hi = (ushort_t*)SplU;
    ushort_t* xs_lo = xs_hi + SPL_US * (size_t)nbat;
    ushort_t* ys_hi = xs_lo + SPL_US * (size_t)nbat;
    ushort_t* ys_lo = ys_hi + SPL_US * (size_t)nbat;
    float* tmp = SplU;   // splits dead by the time tmp is used

    for (int pass = 0; pass < passes; ++pass) {
        int bofs = pass * nbat;

        norms_kernel<<<dim3(16, nbat), 256, 0, stream>>>(x, nx, bofs);
        norms_kernel<<<dim3(16, nbat), 256, 0, stream>>>(y, ny, bofs);

        if (useMfma) {
            split_kernel<<<dim3(8, 64, nbat), 256, 0, stream>>>(x, xs_hi, xs_lo, SPL_US, bofs);
            split_kernel<<<dim3(8, 64, nbat), 256, 0, stream>>>(y, ys_hi, ys_lo, SPL_US, bofs);
            cosgram_mfma_kernel<<<dim3(32, 32, nbat), 256, 0, stream>>>(
                ys_hi, ys_lo, ys_hi, ys_lo, SPL_US, ny, ny, Amat, NPT, SZ_A, 1);
            cosgram_mfma_kernel<<<dim3(32, 32, nbat), 256, 0, stream>>>(
                ys_hi, ys_lo, xs_hi, xs_lo, SPL_US, ny, nx, Brhs, LDB, SZ_B, 0);
        } else {
            cosgram_kernel<<<dim3(64, 64, nbat), 256, 0, stream>>>(y, y, ny, ny, Amat, NPT, SZ_A, 1, bofs);
            cosgram_kernel<<<dim3(64, 64, nbat), 256, 0, stream>>>(y, x, ny, nx, Brhs, LDB, SZ_B, 0, bofs);
        }
        features_kernel<<<dim3(1024, nbat), 256, 0, stream>>>(pw, pb, Brhs);

        if (useMfma) {
            potf2_kernel<<<dim3(1, 1, nbat), 256, 0, stream>>>(Amat, invL, 0);
            for (int kb = 0; kb < NKB - 1; ++kb) {
                int nt = NKB - 1 - kb;
                trsm_mfma_kernel<<<dim3(nt, 1, nbat), 256, 0, stream>>>(Amat, invL, kb);
                syrk_fact_kernel<<<dim3(nt, nt, nbat), 256, 0, stream>>>(Amat, invL, kb);
            }
            solve_fused_kernel<<<dim3(130, 1, nbat), 256, 0, stream>>>(Amat, Brhs, invL);
        } else {
            for (int kb = 0; kb < NKB; ++kb) {
                potf2_kernel<<<dim3(1, 1, nbat), 256, 0, stream>>>(Amat, invL, kb);
                int nrows = NPT - (kb + 1) * NB;
                if (nrows > 0) {
                    trsm_panel_kernel<<<dim3(nrows / 64, 1, nbat), 256, 0, stream>>>(Amat, invL, kb);
                    int nt = nrows / 64;
                    syrk_kernel<<<dim3(nt, nt, nbat), 256, 0, stream>>>(Amat, kb);
                }
            }
            for (int kb = 0; kb < NKB; ++kb) {
                if (kb > 0)
                    solve_gemm_kernel<<<dim3(65, 1, nbat), 256, 0, stream>>>(Amat, Brhs, kb);
                trsm_apply_kernel<<<dim3(65, 1, nbat), 256, 0, stream>>>(Brhs, invL, kb);
            }
        }

        mu_kernel<<<dim3(64, 1, nbat), 256, 0, stream>>>(Brhs, out, bofs);
        kxx_local_kernel<<<dim3(4, 64, nbat), 256, 0, stream>>>(x, nx, tmp, bofs);
        cov_local_kernel<<<dim3(4, 64, nbat), 256, 0, stream>>>(Brhs, tmp, out, bofs);
    }
}

// Round 6
// 18557.564 us; speedup vs baseline: 2.9170x; 1.2567x over previous
//
#include <hip/hip_runtime.h>
#include <math.h>

#define NPT 4096      // points per image (64x64)
#define CCH 512       // channels
#define NB 64         // cholesky panel size
#define NKB 64        // NPT / NB
#define LDB 4160      // RHS leading dim = NPT + 64 feature cols
#define SIGF 0.1f
#define CEPS 1e-6f
#define PI8 25.132741228718345f   // 8*pi

#define APSTR ((size_t)2080 * 4096)   // packed lower-tri Amat floats per batch
#define ILSTR ((size_t)64 * 4096)     // invL floats per batch

typedef __attribute__((ext_vector_type(8))) short bf16x8;
typedef __attribute__((ext_vector_type(4))) float f32x4;
typedef __attribute__((ext_vector_type(4))) unsigned short us4;
typedef unsigned short ushort_t;

__device__ __forceinline__ size_t tbase(int I, int J) {
    return ((size_t)((I * (I + 1) >> 1) + J)) << 12;   // tile (I,J) base, J<=I
}

__device__ inline ushort_t f2bf_rne(float x) {
    unsigned u = __float_as_uint(x);
    unsigned r = u + 0x7FFFu + ((u >> 16) & 1u);
    return (ushort_t)(r >> 16);
}
__device__ inline float bf2f(ushort_t h) { return __uint_as_float(((unsigned)h) << 16); }

__device__ inline void split4(float4 v, us4& h, us4& l) {
    h[0] = f2bf_rne(v.x); l[0] = f2bf_rne(v.x - bf2f(h[0]));
    h[1] = f2bf_rne(v.y); l[1] = f2bf_rne(v.y - bf2f(h[1]));
    h[2] = f2bf_rne(v.z); l[2] = f2bf_rne(v.z - bf2f(h[2]));
    h[3] = f2bf_rne(v.w); l[3] = f2bf_rne(v.w - bf2f(h[3]));
}

// ---------------- norms: nrm[slot][p] = ||X[slot+bofs,:,p]|| ----------------
__global__ __launch_bounds__(256) void norms_kernel(const float* __restrict__ X,
                                                    float* __restrict__ nrm, int bofs) {
    int slot = blockIdx.y;
    int p = blockIdx.x * 256 + threadIdx.x;
    const float* Xb = X + (size_t)(slot + bofs) * CCH * NPT;
    float s = 0.f;
    #pragma unroll 8
    for (int ch = 0; ch < CCH; ++ch) {
        float v = Xb[(size_t)ch * NPT + p];
        s += v * v;
    }
    nrm[slot * NPT + p] = sqrtf(s);
}

// ---------------- split: X[b][ch][pt] f32 -> Hi/Lo [pt][ch] bf16 (z=1 usage) ----------------
__global__ __launch_bounds__(256) void split_kernel(const float* __restrict__ X,
                                                    ushort_t* __restrict__ Hi,
                                                    ushort_t* __restrict__ Lo,
                                                    int bofs) {
    int ch0 = blockIdx.x * 64, pt0 = blockIdx.y * 64;
    const float* Xb = X + (size_t)bofs * CCH * NPT;
    __shared__ float ls[64][65];
    int tid = threadIdx.x;
    for (int t = tid; t < 4096; t += 256) {
        int chl = t >> 6, ptl = t & 63;
        ls[chl][ptl] = Xb[(size_t)(ch0 + chl) * NPT + pt0 + ptl];
    }
    __syncthreads();
    for (int t = tid; t < 4096; t += 256) {
        int ptl = t >> 6, chl = t & 63;
        float v = ls[chl][ptl];
        ushort_t h = f2bf_rne(v);
        float lo = v - bf2f(h);
        Hi[(size_t)(pt0 + ptl) * CCH + ch0 + chl] = h;
        Lo[(size_t)(pt0 + ptl) * CCH + ch0 + chl] = f2bf_rne(lo);
    }
}

// ------------- gramA (K_yy + sigma I) -> packed lower tiles, MFMA split-bf16 -------------
__global__ __launch_bounds__(256) void gramA_packed_kernel(
    const ushort_t* __restrict__ Yhi, const ushort_t* __restrict__ Ylo,
    const float* __restrict__ nY, float* __restrict__ Cp)
{
    int bx = blockIdx.x, by = blockIdx.y;
    if (bx > by) return;
    int bm = by * 128, bn = bx * 128;

    __shared__ __align__(16) ushort_t Ah[128][40];
    __shared__ __align__(16) ushort_t Al[128][40];
    __shared__ __align__(16) ushort_t Bh[128][40];
    __shared__ __align__(16) ushort_t Bl[128][40];

    int tid = threadIdx.x;
    int lane = tid & 63, wid = tid >> 6;
    int wr = wid >> 1, wc = wid & 1;

    f32x4 acc[4][4];
    #pragma unroll
    for (int i = 0; i < 4; ++i)
        #pragma unroll
        for (int j = 0; j < 4; ++j) acc[i][j] = (f32x4){0.f, 0.f, 0.f, 0.f};

    int arr = tid >> 6;
    int srow = lane >> 2, sc4 = lane & 3;
    const ushort_t* src = (arr == 0 || arr == 2) ? Yhi : Ylo;
    int pbase = (arr < 2) ? bm : bn;
    ushort_t* dst = (arr == 0) ? &Ah[0][0] : (arr == 1) ? &Al[0][0] : (arr == 2) ? &Bh[0][0] : &Bl[0][0];

    for (int k0 = 0; k0 < CCH; k0 += 32) {
        #pragma unroll
        for (int it = 0; it < 8; ++it) {
            int row = it * 16 + srow;
            const ushort_t* g = src + (size_t)(pbase + row) * CCH + k0 + sc4 * 8;
            bf16x8 v = *(const bf16x8*)g;
            *(bf16x8*)(dst + row * 40 + sc4 * 8) = v;
        }
        __syncthreads();
        bf16x8 afh[4], afl[4], bfh[4], bfl[4];
        int kcol = (lane >> 4) * 8;
        #pragma unroll
        for (int mi = 0; mi < 4; ++mi) {
            int r = wr * 64 + mi * 16 + (lane & 15);
            afh[mi] = *(const bf16x8*)&Ah[r][kcol];
            afl[mi] = *(const bf16x8*)&Al[r][kcol];
        }
        #pragma unroll
        for (int nj = 0; nj < 4; ++nj) {
            int r = wc * 64 + nj * 16 + (lane & 15);
            bfh[nj] = *(const bf16x8*)&Bh[r][kcol];
            bfl[nj] = *(const bf16x8*)&Bl[r][kcol];
        }
        #pragma unroll
        for (int mi = 0; mi < 4; ++mi)
            #pragma unroll
            for (int nj = 0; nj < 4; ++nj) {
                acc[mi][nj] = __builtin_amdgcn_mfma_f32_16x16x32_bf16(afh[mi], bfh[nj], acc[mi][nj], 0, 0, 0);
                acc[mi][nj] = __builtin_amdgcn_mfma_f32_16x16x32_bf16(afh[mi], bfl[nj], acc[mi][nj], 0, 0, 0);
                acc[mi][nj] = __builtin_amdgcn_mfma_f32_16x16x32_bf16(afl[mi], bfh[nj], acc[mi][nj], 0, 0, 0);
            }
        __syncthreads();
    }

    int I = (bm >> 6) + wr, J = (bn >> 6) + wc;
    if (J > I) return;
    float* Ct = Cp + tbase(I, J);
    #pragma unroll
    for (int nj = 0; nj < 4; ++nj) {
        int cin = nj * 16 + (lane & 15);
        float nbv = nY[bn + wc * 64 + cin];
        #pragma unroll
        for (int mi = 0; mi < 4; ++mi) {
            f32x4 a = acc[mi][nj];
            #pragma unroll
            for (int q = 0; q < 4; ++q) {
                int rin = mi * 16 + (lane >> 4) * 4 + q;
                float den = nY[bm + wr * 64 + rin] * nbv + CEPS;
                float v = expf(a[q] / den - 1.0f);
                if (I == J && rin == cin) v += SIGF;
                Ct[(rin << 6) + cin] = v;
            }
        }
    }
}

// ------------- gramX (K_yx) -> Brhs row-major; A-side pre-split ys, B-side x split on-the-fly -------------
__global__ __launch_bounds__(256) void gramX_kernel(
    const ushort_t* __restrict__ Yhi, const ushort_t* __restrict__ Ylo,
    const float* __restrict__ Xf,     // x batch base, [ch][pt]
    const float* __restrict__ nY, const float* __restrict__ nX,
    float* __restrict__ Cm)
{
    int bm = blockIdx.y * 128, bn = blockIdx.x * 128;

    __shared__ __align__(16) ushort_t Ah[128][40];
    __shared__ __align__(16) ushort_t Al[128][40];
    __shared__ __align__(16) ushort_t Bh[128][40];
    __shared__ __align__(16) ushort_t Bl[128][40];

    int tid = threadIdx.x;
    int lane = tid & 63, wid = tid >> 6;
    int wr = wid >> 1, wc = wid & 1;

    f32x4 acc[4][4];
    #pragma unroll
    for (int i = 0; i < 4; ++i)
        #pragma unroll
        for (int j = 0; j < 4; ++j) acc[i][j] = (f32x4){0.f, 0.f, 0.f, 0.f};

    int srow = lane >> 2, sc4 = lane & 3;

    for (int k0 = 0; k0 < CCH; k0 += 32) {
        if (tid < 128) {
            const ushort_t* src = (tid < 64) ? Yhi : Ylo;
            ushort_t* dst = (tid < 64) ? &Ah[0][0] : &Al[0][0];
            #pragma unroll
            for (int it = 0; it < 8; ++it) {
                int row = it * 16 + srow;
                bf16x8 v = *(const bf16x8*)(src + (size_t)(bm + row) * CCH + k0 + sc4 * 8);
                *(bf16x8*)(dst + row * 40 + sc4 * 8) = v;
            }
        } else {
            int e0 = (tid - 128) * 8;
            #pragma unroll
            for (int i = 0; i < 8; ++i) {
                int e = e0 + i;
                int ch = e >> 5, p4 = e & 31;
                float4 v = *(const float4*)&Xf[(size_t)(k0 + ch) * NPT + bn + (p4 << 2)];
                us4 h, l;
                split4(v, h, l);
                #pragma unroll
                for (int q = 0; q < 4; ++q) {
                    Bh[(p4 << 2) + q][ch] = h[q];
                    Bl[(p4 << 2) + q][ch] = l[q];
                }
            }
        }
        __syncthreads();
        bf16x8 afh[4], afl[4], bfh[4], bfl[4];
        int kcol = (lane >> 4) * 8;
        #pragma unroll
        for (int mi = 0; mi < 4; ++mi) {
            int r = wr * 64 + mi * 16 + (lane & 15);
            afh[mi] = *(const bf16x8*)&Ah[r][kcol];
            afl[mi] = *(const bf16x8*)&Al[r][kcol];
        }
        #pragma unroll
        for (int nj = 0; nj < 4; ++nj) {
            int r = wc * 64 + nj * 16 + (lane & 15);
            bfh[nj] = *(const bf16x8*)&Bh[r][kcol];
            bfl[nj] = *(const bf16x8*)&Bl[r][kcol];
        }
        #pragma unroll
        for (int mi = 0; mi < 4; ++mi)
            #pragma unroll
            for (int nj = 0; nj < 4; ++nj) {
                acc[mi][nj] = __builtin_amdgcn_mfma_f32_16x16x32_bf16(afh[mi], bfh[nj], acc[mi][nj], 0, 0, 0);
                acc[mi][nj] = __builtin_amdgcn_mfma_f32_16x16x32_bf16(afh[mi], bfl[nj], acc[mi][nj], 0, 0, 0);
                acc[mi][nj] = __builtin_amdgcn_mfma_f32_16x16x32_bf16(afl[mi], bfh[nj], acc[mi][nj], 0, 0, 0);
            }
        __syncthreads();
    }

    #pragma unroll
    for (int nj = 0; nj < 4; ++nj) {
        int col = bn + wc * 64 + nj * 16 + (lane & 15);
        float nbv = nX[col];
        #pragma unroll
        for (int mi = 0; mi < 4; ++mi) {
            f32x4 a = acc[mi][nj];
            #pragma unroll
            for (int q = 0; q < 4; ++q) {
                int row = bm + wr * 64 + mi * 16 + (lane >> 4) * 4 + q;
                float den = nY[row] * nbv + CEPS;
                Cm[(size_t)row * LDB + col] = expf(a[q] / den - 1.0f);
            }
        }
    }
}

// ------------- features -------------
__global__ __launch_bounds__(256) void features_kernel(const float* __restrict__ pw,
                                                       const float* __restrict__ pb,
                                                       float* __restrict__ Brhs) {
    int g = blockIdx.x * 256 + threadIdx.x;
    int q = g >> 6, dd = g & 63;
    int hh = q >> 6, ww = q & 63;
    float gy = -1.0f + (2 * hh + 1) / 64.0f;
    float gx = -1.0f + (2 * ww + 1) / 64.0f;
    float ph = PI8 * (pw[dd * 2 + 0] * gx + pw[dd * 2 + 1] * gy + pb[dd]);
    Brhs[(size_t)q * LDB + NPT + dd] = cosf(ph);
}

// ------------- potf2 on packed diag tile (kb,kb), z=2 -------------
__global__ __launch_bounds__(256) void potf2_packed_kernel(float* __restrict__ AmatP,
                                                           float* __restrict__ invL, int kb) {
    __shared__ float a[NB][NB + 4];
    __shared__ float iv[NB][NB + 4];
    __shared__ float ddiag[NB];
    int slot = blockIdx.z;
    float* Ab = AmatP + (size_t)slot * APSTR + tbase(kb, kb);
    int tid = threadIdx.x;
    int tx = tid & 15, ty = tid >> 4;
    for (int t = tid; t < NB * NB; t += 256) {
        int i = t >> 6, j = t & 63;
        a[i][j] = Ab[(i << 6) + j];
        iv[i][j] = 0.0f;
    }
    __syncthreads();
    for (int j = 0; j < NB; ++j) {
        float ajj = sqrtf(a[j][j]);
        float dinv = 1.0f / ajj;
        if (tid == 0) ddiag[j] = ajj;
        for (int i = j + 1 + tid; i < NB; i += 256) a[i][j] *= dinv;
        for (int c = tid; c <= j; c += 256)
            iv[j][c] = ((c == j ? 1.0f : 0.0f) - iv[j][c]) * dinv;
        __syncthreads();
        for (int i = j + 1 + ty; i < NB; i += 16) {
            float lij = a[i][j];
            for (int jj = j + 1 + tx; jj < NB; jj += 16)
                a[i][jj] -= lij * a[jj][j];
            for (int c = tx; c <= j; c += 16)
                iv[i][c] += lij * iv[j][c];
        }
        __syncthreads();
    }
    float* iL = invL + (size_t)slot * ILSTR + ((size_t)kb << 12);
    for (int t = tid; t < NB * NB; t += 256) {
        int i = t >> 6, j = t & 63;
        if (j < i)       Ab[(i << 6) + j] = a[i][j];
        else if (j == i) Ab[(i << 6) + j] = ddiag[i];
        iL[t] = (j <= i) ? iv[i][j] : 0.0f;
    }
}

// ------------- trsm on packed tile (I,kb): T = T @ invL^T, z=2 -------------
__global__ __launch_bounds__(256) void trsm_packed_kernel(float* __restrict__ AmatP,
                                                          const float* __restrict__ invL, int kb) {
    int slot = blockIdx.z;
    int I = kb + 1 + blockIdx.x;
    float* At = AmatP + (size_t)slot * APSTR + tbase(I, kb);
    const float* iL = invL + (size_t)slot * ILSTR + ((size_t)kb << 12);

    __shared__ __align__(16) ushort_t Aoh[64][72], Aol[64][72];
    __shared__ __align__(16) ushort_t Bh[64][72], Bl[64][72];

    int tid = threadIdx.x, lane = tid & 63, w = tid >> 6;
    int frow = lane & 15, fk = (lane >> 4) << 3;
    f32x4 acc[4];
    #pragma unroll
    for (int j = 0; j < 4; ++j) acc[j] = (f32x4){0, 0, 0, 0};

    for (int e = tid; e < 1024; e += 256) {
        int r = e >> 4, k4 = e & 15;
        us4 h, l;
        float4 v = *(const float4*)&At[(r << 6) + (k4 << 2)];
        split4(v, h, l);
        *(us4*)&Aoh[r][k4 << 2] = h; *(us4*)&Aol[r][k4 << 2] = l;
        float4 u = *(const float4*)&iL[(r << 6) + (k4 << 2)];
        split4(u, h, l);
        *(us4*)&Bh[r][k4 << 2] = h; *(us4*)&Bl[r][k4 << 2] = l;
    }
    __syncthreads();
    #pragma unroll
    for (int kk0 = 0; kk0 < 64; kk0 += 32) {
        bf16x8 ah = *(const bf16x8*)&Aoh[(w << 4) + frow][kk0 + fk];
        bf16x8 al = *(const bf16x8*)&Aol[(w << 4) + frow][kk0 + fk];
        #pragma unroll
        for (int nj = 0; nj < 4; ++nj) {
            bf16x8 bh = *(const bf16x8*)&Bh[(nj << 4) + frow][kk0 + fk];
            bf16x8 bl = *(const bf16x8*)&Bl[(nj << 4) + frow][kk0 + fk];
            acc[nj] = __builtin_amdgcn_mfma_f32_16x16x32_bf16(ah, bh, acc[nj], 0, 0, 0);
            acc[nj] = __builtin_amdgcn_mfma_f32_16x16x32_bf16(ah, bl, acc[nj], 0, 0, 0);
            acc[nj] = __builtin_amdgcn_mfma_f32_16x16x32_bf16(al, bh, acc[nj], 0, 0, 0);
        }
    }
    #pragma unroll
    for (int nj = 0; nj < 4; ++nj)
        #pragma unroll
        for (int q = 0; q < 4; ++q) {
            int rin = (w << 4) + ((lane >> 4) << 2) + q;
            At[(rin << 6) + (nj << 4) + frow] = acc[nj][q];
        }
}

// ------------- syrk on packed tiles + fused potf2 of next diag, z=2 -------------
__global__ __launch_bounds__(256) void syrk_fact_packed_kernel(float* __restrict__ AmatP,
                                                               float* __restrict__ invL, int kb) {
    int bi = blockIdx.y, bj = blockIdx.x;
    if (bj > bi) return;
    int slot = blockIdx.z;
    int I = kb + 1 + bi, J = kb + 1 + bj;
    float* base = AmatP + (size_t)slot * APSTR;
    const float* Pi_t = base + tbase(I, kb);
    const float* Pj_t = base + tbase(J, kb);
    float* Ct = base + tbase(I, J);

    __shared__ __align__(16) char smem[36864];
    ushort_t (*Pih)[72] = (ushort_t(*)[72])(smem);
    ushort_t (*Pil)[72] = (ushort_t(*)[72])(smem + 9216);
    ushort_t (*Pjh)[72] = (ushort_t(*)[72])(smem + 18432);
    ushort_t (*Pjl)[72] = (ushort_t(*)[72])(smem + 27648);
    float (*fa)[68] = (float(*)[68])(smem);
    float (*fiv)[68] = (float(*)[68])(smem + 17408);
    float* fdd = (float*)(smem + 34816);

    int tid = threadIdx.x, lane = tid & 63, w = tid >> 6;
    int frow = lane & 15, fk = (lane >> 4) << 3;
    f32x4 acc[4];
    #pragma unroll
    for (int j = 0; j < 4; ++j) acc[j] = (f32x4){0, 0, 0, 0};

    for (int e = tid; e < 1024; e += 256) {
        int r = e >> 4, k4 = e & 15;
        us4 h, l;
        float4 v = *(const float4*)&Pi_t[(r << 6) + (k4 << 2)];
        split4(v, h, l);
        *(us4*)&Pih[r][k4 << 2] = h; *(us4*)&Pil[r][k4 << 2] = l;
        float4 u = *(const float4*)&Pj_t[(r << 6) + (k4 << 2)];
        split4(u, h, l);
        *(us4*)&Pjh[r][k4 << 2] = h; *(us4*)&Pjl[r][k4 << 2] = l;
    }
    __syncthreads();
    #pragma unroll
    for (int kk0 = 0; kk0 < 64; kk0 += 32) {
        bf16x8 ah = *(const bf16x8*)&Pih[(w << 4) + frow][kk0 + fk];
        bf16x8 al = *(const bf16x8*)&Pil[(w << 4) + frow][kk0 + fk];
        #pragma unroll
        for (int nj = 0; nj < 4; ++nj) {
            bf16x8 bh = *(const bf16x8*)&Pjh[(nj << 4) + frow][kk0 + fk];
            bf16x8 bl = *(const bf16x8*)&Pjl[(nj << 4) + frow][kk0 + fk];
            acc[nj] = __builtin_amdgcn_mfma_f32_16x16x32_bf16(ah, bh, acc[nj], 0, 0, 0);
            acc[nj] = __builtin_amdgcn_mfma_f32_16x16x32_bf16(ah, bl, acc[nj], 0, 0, 0);
            acc[nj] = __builtin_amdgcn_mfma_f32_16x16x32_bf16(al, bh, acc[nj], 0, 0, 0);
        }
    }

    if (!(bi == 0 && bj == 0)) {
        #pragma unroll
        for (int nj = 0; nj < 4; ++nj) {
            int cin = (nj << 4) + frow;
            #pragma unroll
            for (int q = 0; q < 4; ++q) {
                int rin = (w << 4) + ((lane >> 4) << 2) + q;
                Ct[(rin << 6) + cin] -= acc[nj][q];
            }
        }
        return;
    }

    // fused potf2 of updated diag tile (kb+1,kb+1)
    __syncthreads();   // panel LDS (aliased by fa/fiv) no longer read
    #pragma unroll
    for (int nj = 0; nj < 4; ++nj) {
        int cin = (nj << 4) + frow;
        #pragma unroll
        for (int q = 0; q < 4; ++q) {
            int rin = (w << 4) + ((lane >> 4) << 2) + q;
            fa[rin][cin] = Ct[(rin << 6) + cin] - acc[nj][q];
            fiv[rin][cin] = 0.0f;
        }
    }
    __syncthreads();
    int tx = tid & 15, ty = tid >> 4;
    for (int j = 0; j < NB; ++j) {
        float ajj = sqrtf(fa[j][j]);
        float dinv = 1.0f / ajj;
        if (tid == 0) fdd[j] = ajj;
        for (int i = j + 1 + tid; i < NB; i += 256) fa[i][j] *= dinv;
        for (int c = tid; c <= j; c += 256)
            fiv[j][c] = ((c == j ? 1.0f : 0.0f) - fiv[j][c]) * dinv;
        __syncthreads();
        for (int i = j + 1 + ty; i < NB; i += 16) {
            float lij = fa[i][j];
            for (int jj = j + 1 + tx; jj < NB; jj += 16)
                fa[i][jj] -= lij * fa[jj][j];
            for (int c = tx; c <= j; c += 16)
                fiv[i][c] += lij * fiv[j][c];
        }
        __syncthreads();
    }
    float* iL = invL + (size_t)slot * ILSTR + ((size_t)(kb + 1) << 12);
    for (int t = tid; t < NB * NB; t += 256) {
        int i = t >> 6, j = t & 63;
        if (j < i)       Ct[(i << 6) + j] = fa[i][j];
        else if (j == i) Ct[(i << 6) + j] = fdd[i];
        iL[t] = (j <= i) ? fiv[i][j] : 0.0f;
    }
}

// ------------- fused forward solve over packed L: one launch per batch, 130 col-stripe blocks -------------
__global__ __launch_bounds__(256) void solve_fused_kernel(const float* __restrict__ AmatP,
                                                          float* __restrict__ Brhs,
                                                          const float* __restrict__ invL) {
    int n0 = blockIdx.x * 32;
    float* Bb = Brhs;

    __shared__ __align__(16) char smem[52224];
    ushort_t (*Lh)[136] = (ushort_t(*)[136])(smem);            // 17408 B
    ushort_t (*Ll)[136] = (ushort_t(*)[136])(smem + 17408);    // 17408 B
    ushort_t (*Uh)[136] = (ushort_t(*)[136])(smem + 34816);    // 8704 B
    ushort_t (*Ul)[136] = (ushort_t(*)[136])(smem + 43520);    // 8704 B
    float (*invLs)[68]  = (float(*)[68])(smem);                // alias Lh (dead)
    float (*Tds)[36]    = (float(*)[36])(smem + 17408);        // alias Ll (dead)

    int tid = threadIdx.x, lane = tid & 63, w = tid >> 6;
    int frow = lane & 15, fk = (lane >> 4) << 3;

    for (int kb = 0; kb < NKB; ++kb) {
        int rb = kb * NB;
        f32x4 acc[2];
        acc[0] = (f32x4){0, 0, 0, 0};
        acc[1] = (f32x4){0, 0, 0, 0};
        for (int k0 = 0; k0 < rb; k0 += 128) {
            int kc = rb - k0; if (kc > 128) kc = 128;
            int Jt = k0 >> 6;
            const float* t0 = AmatP + tbase(kb, Jt);
            const float* t1 = AmatP + tbase(kb, Jt + 1);   // valid only when kc==128
            if (kc == 128) {
                for (int e = tid; e < 2048; e += 256) {
                    int r = e >> 5, k4 = e & 31;
                    const float* ts = (k4 < 16) ? t0 : t1;
                    us4 h, l;
                    float4 v = *(const float4*)&ts[(r << 6) + ((k4 & 15) << 2)];
                    split4(v, h, l);
                    *(us4*)&Lh[r][k4 << 2] = h; *(us4*)&Ll[r][k4 << 2] = l;
                }
            } else {
                for (int e = tid; e < 1024; e += 256) {
                    int r = e >> 4, k4 = e & 15;
                    us4 h, l;
                    float4 v = *(const float4*)&t0[(r << 6) + (k4 << 2)];
                    split4(v, h, l);
                    *(us4*)&Lh[r][k4 << 2] = h; *(us4*)&Ll[r][k4 << 2] = l;
                }
            }
            for (int e = tid; e < (kc << 3); e += 256) {
                int kk = e >> 3, c4 = e & 7;
                float4 v = *(const float4*)&Bb[(size_t)(k0 + kk) * LDB + n0 + (c4 << 2)];
                int c = c4 << 2;
                ushort_t h0 = f2bf_rne(v.x); Uh[c][kk] = h0;     Ul[c][kk]     = f2bf_rne(v.x - bf2f(h0));
                ushort_t h1 = f2bf_rne(v.y); Uh[c + 1][kk] = h1; Ul[c + 1][kk] = f2bf_rne(v.y - bf2f(h1));
                ushort_t h2 = f2bf_rne(v.z); Uh[c + 2][kk] = h2; Ul[c + 2][kk] = f2bf_rne(v.z - bf2f(h2));
                ushort_t h3 = f2bf_rne(v.w); Uh[c + 3][kk] = h3; Ul[c + 3][kk] = f2bf_rne(v.w - bf2f(h3));
            }
            __syncthreads();
            for (int kk0 = 0; kk0 < kc; kk0 += 32) {
                bf16x8 ah = *(const bf16x8*)&Lh[(w << 4) + frow][kk0 + fk];
                bf16x8 al = *(const bf16x8*)&Ll[(w << 4) + frow][kk0 + fk];
                #pragma unroll
                for (int s = 0; s < 2; ++s) {
                    bf16x8 bh = *(const bf16x8*)&Uh[(s << 4) + frow][kk0 + fk];
                    bf16x8 bl = *(const bf16x8*)&Ul[(s << 4) + frow][kk0 + fk];
                    acc[s] = __builtin_amdgcn_mfma_f32_16x16x32_bf16(ah, bh, acc[s], 0, 0, 0);
                    acc[s] = __builtin_amdgcn_mfma_f32_16x16x32_bf16(ah, bl, acc[s], 0, 0, 0);
                    acc[s] = __builtin_amdgcn_mfma_f32_16x16x32_bf16(al, bh, acc[s], 0, 0, 0);
                }
            }
            __syncthreads();
        }
        // Upd -> Tds (Lh/Ll dead now; invLs/Tds alias them)
        #pragma unroll
        for (int s = 0; s < 2; ++s)
            #pragma unroll
            for (int q = 0; q < 4; ++q)
                Tds[(w << 4) + ((lane >> 4) << 2) + q][(s << 4) + frow] = acc[s][q];
        for (int e = tid; e < 1024; e += 256) {
            int r = e >> 4, k4 = e & 15;
            float4 v = *(const float4*)&invL[((size_t)kb << 12) + (r << 6) + (k4 << 2)];
            int k = k4 << 2;
            invLs[r][k] = v.x; invLs[r][k + 1] = v.y; invLs[r][k + 2] = v.z; invLs[r][k + 3] = v.w;
        }
        __syncthreads();
        for (int e = tid; e < 512; e += 256) {
            int r = e >> 3, c4 = e & 7;
            float4 v = *(const float4*)&Bb[(size_t)(rb + r) * LDB + n0 + (c4 << 2)];
            int c = c4 << 2;
            Tds[r][c]     = v.x - Tds[r][c];
            Tds[r][c + 1] = v.y - Tds[r][c + 1];
            Tds[r][c + 2] = v.z - Tds[r][c + 2];
            Tds[r][c + 3] = v.w - Tds[r][c + 3];
        }
        __syncthreads();
        int r8 = tid >> 5, cc = tid & 31;
        #pragma unroll
        for (int i = 0; i < 8; ++i) {
            int row = (i << 3) + r8;
            float s = 0.f;
            #pragma unroll 16
            for (int k = 0; k < 64; ++k) s += invLs[row][k] * Tds[k][cc];
            Bb[(size_t)(rb + row) * LDB + n0 + cc] = s;
        }
        __threadfence_block();
        __syncthreads();
    }
}

// ------------- mu: out[bofs, dd, p] = sum_q U[q,p] * V[q,dd] -------------
__global__ __launch_bounds__(256) void mu_kernel(const float* __restrict__ Brhs,
                                                 float* __restrict__ out, int bofs) {
    const float* Bb = Brhs;
    int p0 = blockIdx.x * 64;
    __shared__ float Us[16][65];
    __shared__ float Vs[16][65];
    float acc[4][4] = {};
    int tid = threadIdx.x, tx = tid & 15, ty = tid >> 4;
    for (int q0 = 0; q0 < NPT; q0 += 16) {
        for (int t = tid; t < 1024; t += 256) {
            int kk = t >> 6, c = t & 63;
            Us[kk][c] = Bb[(size_t)(q0 + kk) * LDB + p0 + c];
            Vs[kk][c] = Bb[(size_t)(q0 + kk) * LDB + NPT + c];
        }
        __syncthreads();
        #pragma unroll
        for (int kk = 0; kk < 16; ++kk) {
            float uv[4], vv[4];
            #pragma unroll
            for (int i = 0; i < 4; ++i) { uv[i] = Us[kk][ty * 4 + i]; vv[i] = Vs[kk][tx * 4 + i]; }
            #pragma unroll
            for (int i = 0; i < 4; ++i)
                #pragma unroll
                for (int j = 0; j < 4; ++j) acc[i][j] += uv[i] * vv[j];
        }
        __syncthreads();
    }
    #pragma unroll
    for (int i = 0; i < 4; ++i)
        #pragma unroll
        for (int j = 0; j < 4; ++j)
            out[((size_t)bofs * 89 + tx * 4 + j) * NPT + p0 + ty * 4 + i] = acc[i][j];
}

// ------------- kxx_local -------------
__global__ __launch_bounds__(256) void kxx_local_kernel(const float* __restrict__ X,
                                                        const float* __restrict__ nxb,
                                                        float* __restrict__ tmp, int bofs) {
    int r = blockIdx.y;
    int c0 = blockIdx.x * 16;
    const float* Xb = X + (size_t)bofs * CCH * NPT;
    __shared__ float Xs[32][104];
    int tid = threadIdx.x;
    int t0 = tid, t1 = tid + 256;
    int pl0 = t0 / 25, jj0 = t0 % 25;
    int pl1 = t1 / 25, jj1 = t1 % 25;
    int pidx0 = 40 + pl0 + 2;
    int jidx0 = (jj0 / 5) * 20 + pl0 + (jj0 % 5);
    int pidx1 = 40 + pl1 + 2;
    int jidx1 = (jj1 / 5) * 20 + pl1 + (jj1 % 5);
    float acc0 = 0.f, acc1 = 0.f;
    for (int ch0 = 0; ch0 < CCH; ch0 += 32) {
        for (int t = tid; t < 32 * 100; t += 256) {
            int ch = t / 100, i = t % 100;
            int s = i / 20, cc = i % 20;
            int gr = r + s - 2, gc = c0 - 2 + cc;
            float v = 0.f;
            if (gr >= 0 && gr < 64 && gc >= 0 && gc < 64)
                v = Xb[(size_t)(ch0 + ch) * NPT + gr * 64 + gc];
            Xs[ch][i] = v;
        }
        __syncthreads();
        #pragma unroll 8
        for (int kk = 0; kk < 32; ++kk) {
            acc0 += Xs[kk][pidx0] * Xs[kk][jidx0];
            if (t1 < 400) acc1 += Xs[kk][pidx1] * Xs[kk][jidx1];
        }
        __syncthreads();
    }
    {
        int p = r * 64 + c0 + pl0;
        int qr = r + jj0 / 5 - 2, qc = c0 + pl0 + jj0 % 5 - 2;
        float v = 0.f;
        if (qr >= 0 && qr < 64 && qc >= 0 && qc < 64) {
            int q = qr * 64 + qc;
            v = expf(acc0 / (nxb[p] * nxb[q] + CEPS) - 1.0f);
        }
        tmp[(size_t)jj0 * NPT + p] = v;
    }
    if (t1 < 400) {
        int p = r * 64 + c0 + pl1;
        int qr = r + jj1 / 5 - 2, qc = c0 + pl1 + jj1 % 5 - 2;
        float v = 0.f;
        if (qr >= 0 && qr < 64 && qc >= 0 && qc < 64) {
            int q = qr * 64 + qc;
            v = expf(acc1 / (nxb[p] * nxb[q] + CEPS) - 1.0f);
        }
        tmp[(size_t)jj1 * NPT + p] = v;
    }
}

// ------------- cov_local -------------
__global__ __launch_bounds__(256) void cov_local_kernel(const float* __restrict__ Brhs,
                                                        const float* __restrict__ tmp,
                                                        float* __restrict__ out, int bofs) {
    int r = blockIdx.y;
    int c0 = blockIdx.x * 16;
    const float* Ub = Brhs;
    __shared__ float Us[64][104];
    int tid = threadIdx.x;
    int t0 = tid, t1 = tid + 256;
    int pl0 = t0 / 25, jj0 = t0 % 25;
    int pl1 = t1 / 25, jj1 = t1 % 25;
    int pidx0 = 40 + pl0 + 2;
    int jidx0 = (jj0 / 5) * 20 + pl0 + (jj0 % 5);
    int pidx1 = 40 + pl1 + 2;
    int jidx1 = (jj1 / 5) * 20 + pl1 + (jj1 % 5);
    float acc0 = 0.f, acc1 = 0.f;
    for (int q0 = 0; q0 < NPT; q0 += 64) {
        for (int t = tid; t < 64 * 100; t += 256) {
            int qq = t / 100, i = t % 100;
            int s = i / 20, cc = i % 20;
            int gr = r + s - 2, gc = c0 - 2 + cc;
            float v = 0.f;
            if (gr >= 0 && gr < 64 && gc >= 0 && gc < 64)
                v = Ub[(size_t)(q0 + qq) * LDB + gr * 64 + gc];
            Us[qq][i] = v;
        }
        __syncthreads();
        #pragma unroll 8
        for (int kk = 0; kk < 64; ++kk) {
            acc0 += Us[kk][pidx0] * Us[kk][jidx0];
            if (t1 < 400) acc1 += Us[kk][pidx1] * Us[kk][jidx1];
        }
        __syncthreads();
    }
    {
        int p = r * 64 + c0 + pl0;
        int qr = r + jj0 / 5 - 2, qc = c0 + pl0 + jj0 % 5 - 2;
        float v = 0.f;
        if (qr >= 0 && qr < 64 && qc >= 0 && qc < 64)
            v = tmp[(size_t)jj0 * NPT + p] - acc0;
        out[((size_t)bofs * 89 + 64 + jj0) * NPT + p] = v;
    }
    if (t1 < 400) {
        int p = r * 64 + c0 + pl1;
        int qr = r + jj1 / 5 - 2, qc = c0 + pl1 + jj1 % 5 - 2;
        float v = 0.f;
        if (qr >= 0 && qr < 64 && qc >= 0 && qc < 64)
            v = tmp[(size_t)jj1 * NPT + p] - acc1;
        out[((size_t)bofs * 89 + 64 + jj1) * NPT + p] = v;
    }
}

extern "C" void kernel_launch(void* const* d_in, const int* in_sizes, int n_in,
                              void* d_out, int out_size, void* d_ws, size_t ws_size,
                              hipStream_t stream) {
    (void)in_sizes; (void)n_in; (void)out_size;
    const float* x  = (const float*)d_in[0];
    const float* y  = (const float*)d_in[1];
    const float* pw = (const float*)d_in[2];
    const float* pb = (const float*)d_in[3];
    float* out = (float*)d_out;
    float* ws  = (float*)d_ws;

    // layout (floats):
    //  AmatP[2]  : 2 * 8,519,680
    //  Brhs      : 17,039,360
    //  invL[2]   : 2 * 262,144    (slot0 region aliased as tmp in epilogues)
    //  nx[2],ny[2]: 4 * 4096
    //  ysH, ysL  : 2 * 1,048,576
    const size_t NEED = 2 * APSTR + (size_t)NPT * LDB + 2 * ILSTR + 4 * NPT + 2 * ((size_t)NPT * CCH / 2);
    if (ws_size < NEED * sizeof(float)) return;

    float* AmatP = ws;
    float* Brhs  = AmatP + 2 * APSTR;
    float* invL  = Brhs + (size_t)NPT * LDB;
    float* nx    = invL + 2 * ILSTR;
    float* ny    = nx + 2 * NPT;
    float* ysBuf = ny + 2 * NPT;
    ushort_t* ysH = (ushort_t*)ysBuf;
    ushort_t* ysL = ysH + (size_t)NPT * CCH;
    float* tmp = invL;   // aliases invL slot 0 (dead after that batch's solve)

    norms_kernel<<<dim3(16, 2), 256, 0, stream>>>(x, nx, 0);
    norms_kernel<<<dim3(16, 2), 256, 0, stream>>>(y, ny, 0);

    // K_yy grams -> packed lower Amat (per batch; ysBuf reused)
    for (int b = 0; b < 2; ++b) {
        split_kernel<<<dim3(8, 64, 1), 256, 0, stream>>>(y, ysH, ysL, b);
        gramA_packed_kernel<<<dim3(32, 32, 1), 256, 0, stream>>>(
            ysH, ysL, ny + (size_t)b * NPT, AmatP + (size_t)b * APSTR);
    }

    // blocked cholesky, both batches concurrently (z=2)
    potf2_packed_kernel<<<dim3(1, 1, 2), 256, 0, stream>>>(AmatP, invL, 0);
    for (int kb = 0; kb < NKB - 1; ++kb) {
        int nt = NKB - 1 - kb;
        trsm_packed_kernel<<<dim3(nt, 1, 2), 256, 0, stream>>>(AmatP, invL, kb);
        syrk_fact_packed_kernel<<<dim3(nt, nt, 2), 256, 0, stream>>>(AmatP, invL, kb);
    }

    // per batch: K_yx gram -> Brhs, features, fused solve, epilogues
    for (int b = 0; b < 2; ++b) {
        split_kernel<<<dim3(8, 64, 1), 256, 0, stream>>>(y, ysH, ysL, b);
        features_kernel<<<dim3(1024, 1), 256, 0, stream>>>(pw, pb, Brhs);
        gramX_kernel<<<dim3(32, 32, 1), 256, 0, stream>>>(
            ysH, ysL, x + (size_t)b * CCH * NPT, ny + (size_t)b * NPT, nx + (size_t)b * NPT, Brhs);
        solve_fused_kernel<<<dim3(130, 1, 1), 256, 0, stream>>>(
            AmatP + (size_t)b * APSTR, Brhs, invL + (size_t)b * ILSTR);
        mu_kernel<<<dim3(64, 1, 1), 256, 0, stream>>>(Brhs, out, b);
        kxx_local_kernel<<<dim3(4, 64, 1), 256, 0, stream>>>(x, nx + (size_t)b * NPT, tmp, b);
        cov_local_kernel<<<dim3(4, 64, 1), 256, 0, stream>>>(Brhs, tmp, out, b);
    }
}

// Round 7
// 11393.950 us; speedup vs baseline: 4.7510x; 1.6287x over previous
//
#include <hip/hip_runtime.h>
#include <math.h>

#define NPT 4096      // points per image (64x64)
#define CCH 512       // channels
#define NB 64         // cholesky panel size
#define NKB 64        // NPT / NB
#define LDB 4160      // RHS leading dim = NPT + 64 feature cols
#define SIGF 0.1f
#define CEPS 1e-6f
#define PI8 25.132741228718345f   // 8*pi

#define APSTR ((size_t)2080 * 4096)   // packed lower-tri Amat floats per batch
#define ILSTR ((size_t)64 * 4096)     // invL floats per batch

typedef __attribute__((ext_vector_type(8))) short bf16x8;
typedef __attribute__((ext_vector_type(4))) float f32x4;
typedef __attribute__((ext_vector_type(4))) unsigned short us4;
typedef unsigned short ushort_t;

__device__ __forceinline__ size_t tbase(int I, int J) {
    return ((size_t)((I * (I + 1) >> 1) + J)) << 12;   // tile (I,J) base, J<=I
}

__device__ inline ushort_t f2bf_rne(float x) {
    unsigned u = __float_as_uint(x);
    unsigned r = u + 0x7FFFu + ((u >> 16) & 1u);
    return (ushort_t)(r >> 16);
}
__device__ inline float bf2f(ushort_t h) { return __uint_as_float(((unsigned)h) << 16); }

__device__ inline void split4(float4 v, us4& h, us4& l) {
    h[0] = f2bf_rne(v.x); l[0] = f2bf_rne(v.x - bf2f(h[0]));
    h[1] = f2bf_rne(v.y); l[1] = f2bf_rne(v.y - bf2f(h[1]));
    h[2] = f2bf_rne(v.z); l[2] = f2bf_rne(v.z - bf2f(h[2]));
    h[3] = f2bf_rne(v.w); l[3] = f2bf_rne(v.w - bf2f(h[3]));
}

// ---------------- norms ----------------
__global__ __launch_bounds__(256) void norms_kernel(const float* __restrict__ X,
                                                    float* __restrict__ nrm, int bofs) {
    int slot = blockIdx.y;
    int p = blockIdx.x * 256 + threadIdx.x;
    const float* Xb = X + (size_t)(slot + bofs) * CCH * NPT;
    float s = 0.f;
    #pragma unroll 8
    for (int ch = 0; ch < CCH; ++ch) {
        float v = Xb[(size_t)ch * NPT + p];
        s += v * v;
    }
    nrm[slot * NPT + p] = sqrtf(s);
}

// ---------------- split: X[b][ch][pt] f32 -> Hi/Lo [pt][ch] bf16 ----------------
__global__ __launch_bounds__(256) void split_kernel(const float* __restrict__ X,
                                                    ushort_t* __restrict__ Hi,
                                                    ushort_t* __restrict__ Lo,
                                                    int bofs) {
    int ch0 = blockIdx.x * 64, pt0 = blockIdx.y * 64;
    const float* Xb = X + (size_t)bofs * CCH * NPT;
    __shared__ float ls[64][65];
    int tid = threadIdx.x;
    for (int t = tid; t < 4096; t += 256) {
        int chl = t >> 6, ptl = t & 63;
        ls[chl][ptl] = Xb[(size_t)(ch0 + chl) * NPT + pt0 + ptl];
    }
    __syncthreads();
    for (int t = tid; t < 4096; t += 256) {
        int ptl = t >> 6, chl = t & 63;
        float v = ls[chl][ptl];
        ushort_t h = f2bf_rne(v);
        float lo = v - bf2f(h);
        Hi[(size_t)(pt0 + ptl) * CCH + ch0 + chl] = h;
        Lo[(size_t)(pt0 + ptl) * CCH + ch0 + chl] = f2bf_rne(lo);
    }
}

// ------------- gramA (K_yy + sigma I) -> packed lower tiles, MFMA split-bf16 -------------
__global__ __launch_bounds__(256) void gramA_packed_kernel(
    const ushort_t* __restrict__ Yhi, const ushort_t* __restrict__ Ylo,
    const float* __restrict__ nY, float* __restrict__ Cp)
{
    int bx = blockIdx.x, by = blockIdx.y;
    if (bx > by) return;
    int bm = by * 128, bn = bx * 128;

    __shared__ __align__(16) ushort_t Ah[128][40];
    __shared__ __align__(16) ushort_t Al[128][40];
    __shared__ __align__(16) ushort_t Bh[128][40];
    __shared__ __align__(16) ushort_t Bl[128][40];

    int tid = threadIdx.x;
    int lane = tid & 63, wid = tid >> 6;
    int wr = wid >> 1, wc = wid & 1;

    f32x4 acc[4][4];
    #pragma unroll
    for (int i = 0; i < 4; ++i)
        #pragma unroll
        for (int j = 0; j < 4; ++j) acc[i][j] = (f32x4){0.f, 0.f, 0.f, 0.f};

    int arr = tid >> 6;
    int srow = lane >> 2, sc4 = lane & 3;
    const ushort_t* src = (arr == 0 || arr == 2) ? Yhi : Ylo;
    int pbase = (arr < 2) ? bm : bn;
    ushort_t* dst = (arr == 0) ? &Ah[0][0] : (arr == 1) ? &Al[0][0] : (arr == 2) ? &Bh[0][0] : &Bl[0][0];

    for (int k0 = 0; k0 < CCH; k0 += 32) {
        #pragma unroll
        for (int it = 0; it < 8; ++it) {
            int row = it * 16 + srow;
            const ushort_t* g = src + (size_t)(pbase + row) * CCH + k0 + sc4 * 8;
            bf16x8 v = *(const bf16x8*)g;
            *(bf16x8*)(dst + row * 40 + sc4 * 8) = v;
        }
        __syncthreads();
        bf16x8 afh[4], afl[4], bfh[4], bfl[4];
        int kcol = (lane >> 4) * 8;
        #pragma unroll
        for (int mi = 0; mi < 4; ++mi) {
            int r = wr * 64 + mi * 16 + (lane & 15);
            afh[mi] = *(const bf16x8*)&Ah[r][kcol];
            afl[mi] = *(const bf16x8*)&Al[r][kcol];
        }
        #pragma unroll
        for (int nj = 0; nj < 4; ++nj) {
            int r = wc * 64 + nj * 16 + (lane & 15);
            bfh[nj] = *(const bf16x8*)&Bh[r][kcol];
            bfl[nj] = *(const bf16x8*)&Bl[r][kcol];
        }
        #pragma unroll
        for (int mi = 0; mi < 4; ++mi)
            #pragma unroll
            for (int nj = 0; nj < 4; ++nj) {
                acc[mi][nj] = __builtin_amdgcn_mfma_f32_16x16x32_bf16(afh[mi], bfh[nj], acc[mi][nj], 0, 0, 0);
                acc[mi][nj] = __builtin_amdgcn_mfma_f32_16x16x32_bf16(afh[mi], bfl[nj], acc[mi][nj], 0, 0, 0);
                acc[mi][nj] = __builtin_amdgcn_mfma_f32_16x16x32_bf16(afl[mi], bfh[nj], acc[mi][nj], 0, 0, 0);
            }
        __syncthreads();
    }

    int I = (bm >> 6) + wr, J = (bn >> 6) + wc;
    if (J > I) return;
    float* Ct = Cp + tbase(I, J);
    #pragma unroll
    for (int nj = 0; nj < 4; ++nj) {
        int cin = nj * 16 + (lane & 15);
        float nbv = nY[bn + wc * 64 + cin];
        #pragma unroll
        for (int mi = 0; mi < 4; ++mi) {
            f32x4 a = acc[mi][nj];
            #pragma unroll
            for (int q = 0; q < 4; ++q) {
                int rin = mi * 16 + (lane >> 4) * 4 + q;
                float den = nY[bm + wr * 64 + rin] * nbv + CEPS;
                float v = expf(a[q] / den - 1.0f);
                if (I == J && rin == cin) v += SIGF;
                Ct[(rin << 6) + cin] = v;
            }
        }
    }
}

// ------------- gramX (K_yx) -> Brhs row-major -------------
__global__ __launch_bounds__(256) void gramX_kernel(
    const ushort_t* __restrict__ Yhi, const ushort_t* __restrict__ Ylo,
    const float* __restrict__ Xf,
    const float* __restrict__ nY, const float* __restrict__ nX,
    float* __restrict__ Cm)
{
    int bm = blockIdx.y * 128, bn = blockIdx.x * 128;

    __shared__ __align__(16) ushort_t Ah[128][40];
    __shared__ __align__(16) ushort_t Al[128][40];
    __shared__ __align__(16) ushort_t Bh[128][40];
    __shared__ __align__(16) ushort_t Bl[128][40];

    int tid = threadIdx.x;
    int lane = tid & 63, wid = tid >> 6;
    int wr = wid >> 1, wc = wid & 1;

    f32x4 acc[4][4];
    #pragma unroll
    for (int i = 0; i < 4; ++i)
        #pragma unroll
        for (int j = 0; j < 4; ++j) acc[i][j] = (f32x4){0.f, 0.f, 0.f, 0.f};

    int srow = lane >> 2, sc4 = lane & 3;

    for (int k0 = 0; k0 < CCH; k0 += 32) {
        if (tid < 128) {
            const ushort_t* src = (tid < 64) ? Yhi : Ylo;
            ushort_t* dst = (tid < 64) ? &Ah[0][0] : &Al[0][0];
            #pragma unroll
            for (int it = 0; it < 8; ++it) {
                int row = it * 16 + srow;
                bf16x8 v = *(const bf16x8*)(src + (size_t)(bm + row) * CCH + k0 + sc4 * 8);
                *(bf16x8*)(dst + row * 40 + sc4 * 8) = v;
            }
        } else {
            int e0 = (tid - 128) * 8;
            #pragma unroll
            for (int i = 0; i < 8; ++i) {
                int e = e0 + i;
                int ch = e >> 5, p4 = e & 31;
                float4 v = *(const float4*)&Xf[(size_t)(k0 + ch) * NPT + bn + (p4 << 2)];
                us4 h, l;
                split4(v, h, l);
                #pragma unroll
                for (int q = 0; q < 4; ++q) {
                    Bh[(p4 << 2) + q][ch] = h[q];
                    Bl[(p4 << 2) + q][ch] = l[q];
                }
            }
        }
        __syncthreads();
        bf16x8 afh[4], afl[4], bfh[4], bfl[4];
        int kcol = (lane >> 4) * 8;
        #pragma unroll
        for (int mi = 0; mi < 4; ++mi) {
            int r = wr * 64 + mi * 16 + (lane & 15);
            afh[mi] = *(const bf16x8*)&Ah[r][kcol];
            afl[mi] = *(const bf16x8*)&Al[r][kcol];
        }
        #pragma unroll
        for (int nj = 0; nj < 4; ++nj) {
            int r = wc * 64 + nj * 16 + (lane & 15);
            bfh[nj] = *(const bf16x8*)&Bh[r][kcol];
            bfl[nj] = *(const bf16x8*)&Bl[r][kcol];
        }
        #pragma unroll
        for (int mi = 0; mi < 4; ++mi)
            #pragma unroll
            for (int nj = 0; nj < 4; ++nj) {
                acc[mi][nj] = __builtin_amdgcn_mfma_f32_16x16x32_bf16(afh[mi], bfh[nj], acc[mi][nj], 0, 0, 0);
                acc[mi][nj] = __builtin_amdgcn_mfma_f32_16x16x32_bf16(afh[mi], bfl[nj], acc[mi][nj], 0, 0, 0);
                acc[mi][nj] = __builtin_amdgcn_mfma_f32_16x16x32_bf16(afl[mi], bfh[nj], acc[mi][nj], 0, 0, 0);
            }
        __syncthreads();
    }

    #pragma unroll
    for (int nj = 0; nj < 4; ++nj) {
        int col = bn + wc * 64 + nj * 16 + (lane & 15);
        float nbv = nX[col];
        #pragma unroll
        for (int mi = 0; mi < 4; ++mi) {
            f32x4 a = acc[mi][nj];
            #pragma unroll
            for (int q = 0; q < 4; ++q) {
                int row = bm + wr * 64 + mi * 16 + (lane >> 4) * 4 + q;
                float den = nY[row] * nbv + CEPS;
                Cm[(size_t)row * LDB + col] = expf(a[q] / den - 1.0f);
            }
        }
    }
}

// ------------- features -------------
__global__ __launch_bounds__(256) void features_kernel(const float* __restrict__ pw,
                                                       const float* __restrict__ pb,
                                                       float* __restrict__ Brhs) {
    int g = blockIdx.x * 256 + threadIdx.x;
    int q = g >> 6, dd = g & 63;
    int hh = q >> 6, ww = q & 63;
    float gy = -1.0f + (2 * hh + 1) / 64.0f;
    float gx = -1.0f + (2 * ww + 1) / 64.0f;
    float ph = PI8 * (pw[dd * 2 + 0] * gx + pw[dd * 2 + 1] * gy + pb[dd]);
    Brhs[(size_t)q * LDB + NPT + dd] = cosf(ph);
}

// ------------- potf2 on packed diag tile (kb,kb), z=2 -------------
__global__ __launch_bounds__(256) void potf2_packed_kernel(float* __restrict__ AmatP,
                                                           float* __restrict__ invL, int kb) {
    __shared__ float a[NB][NB + 4];
    __shared__ float iv[NB][NB + 4];
    __shared__ float ddiag[NB];
    int slot = blockIdx.z;
    float* Ab = AmatP + (size_t)slot * APSTR + tbase(kb, kb);
    int tid = threadIdx.x;
    int tx = tid & 15, ty = tid >> 4;
    for (int t = tid; t < NB * NB; t += 256) {
        int i = t >> 6, j = t & 63;
        a[i][j] = Ab[(i << 6) + j];
        iv[i][j] = 0.0f;
    }
    __syncthreads();
    for (int j = 0; j < NB; ++j) {
        float ajj = sqrtf(a[j][j]);
        float dinv = 1.0f / ajj;
        if (tid == 0) ddiag[j] = ajj;
        for (int i = j + 1 + tid; i < NB; i += 256) a[i][j] *= dinv;
        for (int c = tid; c <= j; c += 256)
            iv[j][c] = ((c == j ? 1.0f : 0.0f) - iv[j][c]) * dinv;
        __syncthreads();
        for (int i = j + 1 + ty; i < NB; i += 16) {
            float lij = a[i][j];
            for (int jj = j + 1 + tx; jj < NB; jj += 16)
                a[i][jj] -= lij * a[jj][j];
            for (int c = tx; c <= j; c += 16)
                iv[i][c] += lij * iv[j][c];
        }
        __syncthreads();
    }
    float* iL = invL + (size_t)slot * ILSTR + ((size_t)kb << 12);
    for (int t = tid; t < NB * NB; t += 256) {
        int i = t >> 6, j = t & 63;
        if (j < i)       Ab[(i << 6) + j] = a[i][j];
        else if (j == i) Ab[(i << 6) + j] = ddiag[i];
        iL[t] = (j <= i) ? iv[i][j] : 0.0f;
    }
}

// ------------- trsm on packed tile (I,kb): T = T @ invL^T, z=2 -------------
__global__ __launch_bounds__(256) void trsm_packed_kernel(float* __restrict__ AmatP,
                                                          const float* __restrict__ invL, int kb) {
    int slot = blockIdx.z;
    int I = kb + 1 + blockIdx.x;
    float* At = AmatP + (size_t)slot * APSTR + tbase(I, kb);
    const float* iL = invL + (size_t)slot * ILSTR + ((size_t)kb << 12);

    __shared__ __align__(16) ushort_t Aoh[64][72], Aol[64][72];
    __shared__ __align__(16) ushort_t Bh[64][72], Bl[64][72];

    int tid = threadIdx.x, lane = tid & 63, w = tid >> 6;
    int frow = lane & 15, fk = (lane >> 4) << 3;
    f32x4 acc[4];
    #pragma unroll
    for (int j = 0; j < 4; ++j) acc[j] = (f32x4){0, 0, 0, 0};

    for (int e = tid; e < 1024; e += 256) {
        int r = e >> 4, k4 = e & 15;
        us4 h, l;
        float4 v = *(const float4*)&At[(r << 6) + (k4 << 2)];
        split4(v, h, l);
        *(us4*)&Aoh[r][k4 << 2] = h; *(us4*)&Aol[r][k4 << 2] = l;
        float4 u = *(const float4*)&iL[(r << 6) + (k4 << 2)];
        split4(u, h, l);
        *(us4*)&Bh[r][k4 << 2] = h; *(us4*)&Bl[r][k4 << 2] = l;
    }
    __syncthreads();
    #pragma unroll
    for (int kk0 = 0; kk0 < 64; kk0 += 32) {
        bf16x8 ah = *(const bf16x8*)&Aoh[(w << 4) + frow][kk0 + fk];
        bf16x8 al = *(const bf16x8*)&Aol[(w << 4) + frow][kk0 + fk];
        #pragma unroll
        for (int nj = 0; nj < 4; ++nj) {
            bf16x8 bh = *(const bf16x8*)&Bh[(nj << 4) + frow][kk0 + fk];
            bf16x8 bl = *(const bf16x8*)&Bl[(nj << 4) + frow][kk0 + fk];
            acc[nj] = __builtin_amdgcn_mfma_f32_16x16x32_bf16(ah, bh, acc[nj], 0, 0, 0);
            acc[nj] = __builtin_amdgcn_mfma_f32_16x16x32_bf16(ah, bl, acc[nj], 0, 0, 0);
            acc[nj] = __builtin_amdgcn_mfma_f32_16x16x32_bf16(al, bh, acc[nj], 0, 0, 0);
        }
    }
    #pragma unroll
    for (int nj = 0; nj < 4; ++nj)
        #pragma unroll
        for (int q = 0; q < 4; ++q) {
            int rin = (w << 4) + ((lane >> 4) << 2) + q;
            At[(rin << 6) + (nj << 4) + frow] = acc[nj][q];
        }
}

// ------------- syrk on packed tiles + fused potf2 of next diag, z=2 -------------
__global__ __launch_bounds__(256) void syrk_fact_packed_kernel(float* __restrict__ AmatP,
                                                               float* __restrict__ invL, int kb) {
    int bi = blockIdx.y, bj = blockIdx.x;
    if (bj > bi) return;
    int slot = blockIdx.z;
    int I = kb + 1 + bi, J = kb + 1 + bj;
    float* base = AmatP + (size_t)slot * APSTR;
    const float* Pi_t = base + tbase(I, kb);
    const float* Pj_t = base + tbase(J, kb);
    float* Ct = base + tbase(I, J);

    __shared__ __align__(16) char smem[36864];
    ushort_t (*Pih)[72] = (ushort_t(*)[72])(smem);
    ushort_t (*Pil)[72] = (ushort_t(*)[72])(smem + 9216);
    ushort_t (*Pjh)[72] = (ushort_t(*)[72])(smem + 18432);
    ushort_t (*Pjl)[72] = (ushort_t(*)[72])(smem + 27648);
    float (*fa)[68] = (float(*)[68])(smem);
    float (*fiv)[68] = (float(*)[68])(smem + 17408);
    float* fdd = (float*)(smem + 34816);

    int tid = threadIdx.x, lane = tid & 63, w = tid >> 6;
    int frow = lane & 15, fk = (lane >> 4) << 3;
    f32x4 acc[4];
    #pragma unroll
    for (int j = 0; j < 4; ++j) acc[j] = (f32x4){0, 0, 0, 0};

    for (int e = tid; e < 1024; e += 256) {
        int r = e >> 4, k4 = e & 15;
        us4 h, l;
        float4 v = *(const float4*)&Pi_t[(r << 6) + (k4 << 2)];
        split4(v, h, l);
        *(us4*)&Pih[r][k4 << 2] = h; *(us4*)&Pil[r][k4 << 2] = l;
        float4 u = *(const float4*)&Pj_t[(r << 6) + (k4 << 2)];
        split4(u, h, l);
        *(us4*)&Pjh[r][k4 << 2] = h; *(us4*)&Pjl[r][k4 << 2] = l;
    }
    __syncthreads();
    #pragma unroll
    for (int kk0 = 0; kk0 < 64; kk0 += 32) {
        bf16x8 ah = *(const bf16x8*)&Pih[(w << 4) + frow][kk0 + fk];
        bf16x8 al = *(const bf16x8*)&Pil[(w << 4) + frow][kk0 + fk];
        #pragma unroll
        for (int nj = 0; nj < 4; ++nj) {
            bf16x8 bh = *(const bf16x8*)&Pjh[(nj << 4) + frow][kk0 + fk];
            bf16x8 bl = *(const bf16x8*)&Pjl[(nj << 4) + frow][kk0 + fk];
            acc[nj] = __builtin_amdgcn_mfma_f32_16x16x32_bf16(ah, bh, acc[nj], 0, 0, 0);
            acc[nj] = __builtin_amdgcn_mfma_f32_16x16x32_bf16(ah, bl, acc[nj], 0, 0, 0);
            acc[nj] = __builtin_amdgcn_mfma_f32_16x16x32_bf16(al, bh, acc[nj], 0, 0, 0);
        }
    }

    if (!(bi == 0 && bj == 0)) {
        #pragma unroll
        for (int nj = 0; nj < 4; ++nj) {
            int cin = (nj << 4) + frow;
            #pragma unroll
            for (int q = 0; q < 4; ++q) {
                int rin = (w << 4) + ((lane >> 4) << 2) + q;
                Ct[(rin << 6) + cin] -= acc[nj][q];
            }
        }
        return;
    }

    __syncthreads();
    #pragma unroll
    for (int nj = 0; nj < 4; ++nj) {
        int cin = (nj << 4) + frow;
        #pragma unroll
        for (int q = 0; q < 4; ++q) {
            int rin = (w << 4) + ((lane >> 4) << 2) + q;
            fa[rin][cin] = Ct[(rin << 6) + cin] - acc[nj][q];
            fiv[rin][cin] = 0.0f;
        }
    }
    __syncthreads();
    int tx = tid & 15, ty = tid >> 4;
    for (int j = 0; j < NB; ++j) {
        float ajj = sqrtf(fa[j][j]);
        float dinv = 1.0f / ajj;
        if (tid == 0) fdd[j] = ajj;
        for (int i = j + 1 + tid; i < NB; i += 256) fa[i][j] *= dinv;
        for (int c = tid; c <= j; c += 256)
            fiv[j][c] = ((c == j ? 1.0f : 0.0f) - fiv[j][c]) * dinv;
        __syncthreads();
        for (int i = j + 1 + ty; i < NB; i += 16) {
            float lij = fa[i][j];
            for (int jj = j + 1 + tx; jj < NB; jj += 16)
                fa[i][jj] -= lij * fa[jj][j];
            for (int c = tx; c <= j; c += 16)
                fiv[i][c] += lij * fiv[j][c];
        }
        __syncthreads();
    }
    float* iL = invL + (size_t)slot * ILSTR + ((size_t)(kb + 1) << 12);
    for (int t = tid; t < NB * NB; t += 256) {
        int i = t >> 6, j = t & 63;
        if (j < i)       Ct[(i << 6) + j] = fa[i][j];
        else if (j == i) Ct[(i << 6) + j] = fdd[i];
        iL[t] = (j <= i) ? fiv[i][j] : 0.0f;
    }
}

// ------------- prologue: U[0] = invL[0] @ B[0] (f32), 65 col-stripe blocks -------------
__global__ __launch_bounds__(256) void trsm_rhs_kernel(float* __restrict__ Brhs,
                                                       const float* __restrict__ invL) {
    int n0 = blockIdx.x * 64;
    __shared__ float invLs[64][68];
    __shared__ float Tds[64][68];
    int tid = threadIdx.x;
    for (int e = tid; e < 1024; e += 256) {
        int r = e >> 4, k4 = e & 15;
        float4 v = *(const float4*)&Brhs[(size_t)r * LDB + n0 + (k4 << 2)];
        int c = k4 << 2;
        Tds[r][c] = v.x; Tds[r][c + 1] = v.y; Tds[r][c + 2] = v.z; Tds[r][c + 3] = v.w;
        float4 u = *(const float4*)&invL[(r << 6) + (k4 << 2)];
        invLs[r][c] = u.x; invLs[r][c + 1] = u.y; invLs[r][c + 2] = u.z; invLs[r][c + 3] = u.w;
    }
    __syncthreads();
    int col = tid & 63, rg = tid >> 6;
    #pragma unroll
    for (int i = 0; i < 16; ++i) {
        int r = (i << 2) + rg;
        float s = 0.f;
        #pragma unroll 16
        for (int k = 0; k < 64; ++k) s += invLs[r][k] * Tds[k][col];
        Brhs[(size_t)r * LDB + n0 + col] = s;
    }
}

// ------------- solve step kb: grid(65, 63-kb). All blocks: P = L[I,kb] @ U[kb].
//   by>0:  B[I] -= P
//   by==0 (I=kb+1): U[kb+1] = invL[kb+1] @ (B[I] - P)   (f32 trsm tail) -------------
__global__ __launch_bounds__(256) void solve_step_kernel(const float* __restrict__ AmatP,
                                                         float* __restrict__ Brhs,
                                                         const float* __restrict__ invL, int kb) {
    int n0 = blockIdx.x * 64;
    int I = kb + 1 + blockIdx.y;
    int rb = kb * NB;           // U[kb] rows
    int ri = I * NB;            // target rows
    const float* Lt = AmatP + tbase(I, kb);

    __shared__ __align__(16) char smem[36864];
    ushort_t (*Lh)[72] = (ushort_t(*)[72])(smem);             // 9216
    ushort_t (*Ll)[72] = (ushort_t(*)[72])(smem + 9216);      // 9216
    ushort_t (*Uh)[72] = (ushort_t(*)[72])(smem + 18432);     // [c][k] transposed
    ushort_t (*Ul)[72] = (ushort_t(*)[72])(smem + 27648);
    float (*invLs)[68] = (float(*)[68])(smem);                // alias Lh/Ll (dead after MFMA)
    float (*Tds)[68]   = (float(*)[68])(smem + 18432);        // alias Uh/Ul

    int tid = threadIdx.x, lane = tid & 63, w = tid >> 6;
    int frow = lane & 15, fk = (lane >> 4) << 3;

    for (int e = tid; e < 1024; e += 256) {
        int r = e >> 4, k4 = e & 15;
        us4 h, l;
        float4 v = *(const float4*)&Lt[(r << 6) + (k4 << 2)];
        split4(v, h, l);
        *(us4*)&Lh[r][k4 << 2] = h; *(us4*)&Ll[r][k4 << 2] = l;
        // U[kb] rows (k = r), cols n0+(k4*4..+3): store transposed [c][k]
        float4 u = *(const float4*)&Brhs[(size_t)(rb + r) * LDB + n0 + (k4 << 2)];
        split4(u, h, l);
        #pragma unroll
        for (int q = 0; q < 4; ++q) {
            Uh[(k4 << 2) + q][r] = h[q];
            Ul[(k4 << 2) + q][r] = l[q];
        }
    }
    __syncthreads();

    f32x4 acc[4];
    #pragma unroll
    for (int j = 0; j < 4; ++j) acc[j] = (f32x4){0, 0, 0, 0};
    #pragma unroll
    for (int kk0 = 0; kk0 < 64; kk0 += 32) {
        bf16x8 ah = *(const bf16x8*)&Lh[(w << 4) + frow][kk0 + fk];
        bf16x8 al = *(const bf16x8*)&Ll[(w << 4) + frow][kk0 + fk];
        #pragma unroll
        for (int nj = 0; nj < 4; ++nj) {
            bf16x8 bh = *(const bf16x8*)&Uh[(nj << 4) + frow][kk0 + fk];
            bf16x8 bl = *(const bf16x8*)&Ul[(nj << 4) + frow][kk0 + fk];
            acc[nj] = __builtin_amdgcn_mfma_f32_16x16x32_bf16(ah, bh, acc[nj], 0, 0, 0);
            acc[nj] = __builtin_amdgcn_mfma_f32_16x16x32_bf16(ah, bl, acc[nj], 0, 0, 0);
            acc[nj] = __builtin_amdgcn_mfma_f32_16x16x32_bf16(al, bh, acc[nj], 0, 0, 0);
        }
    }

    if (blockIdx.y > 0) {
        #pragma unroll
        for (int nj = 0; nj < 4; ++nj) {
            int cin = (nj << 4) + frow;
            #pragma unroll
            for (int q = 0; q < 4; ++q) {
                int rin = (w << 4) + ((lane >> 4) << 2) + q;
                Brhs[(size_t)(ri + rin) * LDB + n0 + cin] -= acc[nj][q];
            }
        }
        return;
    }

    // by==0: trsm tail.  Alias Tds/invLs over the (now dead) bf16 tiles.
    __syncthreads();
    #pragma unroll
    for (int nj = 0; nj < 4; ++nj) {
        int cin = (nj << 4) + frow;
        #pragma unroll
        for (int q = 0; q < 4; ++q) {
            int rin = (w << 4) + ((lane >> 4) << 2) + q;
            Tds[rin][cin] = Brhs[(size_t)(ri + rin) * LDB + n0 + cin] - acc[nj][q];
        }
    }
    const float* iL = invL + ((size_t)(kb + 1) << 12);
    for (int e = tid; e < 1024; e += 256) {
        int r = e >> 4, k4 = e & 15;
        float4 u = *(const float4*)&iL[(r << 6) + (k4 << 2)];
        int c = k4 << 2;
        invLs[r][c] = u.x; invLs[r][c + 1] = u.y; invLs[r][c + 2] = u.z; invLs[r][c + 3] = u.w;
    }
    __syncthreads();
    int col = tid & 63, rg = tid >> 6;
    #pragma unroll
    for (int i = 0; i < 16; ++i) {
        int r = (i << 2) + rg;
        float s = 0.f;
        #pragma unroll 16
        for (int k = 0; k < 64; ++k) s += invLs[r][k] * Tds[k][col];
        Brhs[(size_t)(ri + r) * LDB + n0 + col] = s;
    }
}

// ------------- mu -------------
__global__ __launch_bounds__(256) void mu_kernel(const float* __restrict__ Brhs,
                                                 float* __restrict__ out, int bofs) {
    const float* Bb = Brhs;
    int p0 = blockIdx.x * 64;
    __shared__ float Us[16][65];
    __shared__ float Vs[16][65];
    float acc[4][4] = {};
    int tid = threadIdx.x, tx = tid & 15, ty = tid >> 4;
    for (int q0 = 0; q0 < NPT; q0 += 16) {
        for (int t = tid; t < 1024; t += 256) {
            int kk = t >> 6, c = t & 63;
            Us[kk][c] = Bb[(size_t)(q0 + kk) * LDB + p0 + c];
            Vs[kk][c] = Bb[(size_t)(q0 + kk) * LDB + NPT + c];
        }
        __syncthreads();
        #pragma unroll
        for (int kk = 0; kk < 16; ++kk) {
            float uv[4], vv[4];
            #pragma unroll
            for (int i = 0; i < 4; ++i) { uv[i] = Us[kk][ty * 4 + i]; vv[i] = Vs[kk][tx * 4 + i]; }
            #pragma unroll
            for (int i = 0; i < 4; ++i)
                #pragma unroll
                for (int j = 0; j < 4; ++j) acc[i][j] += uv[i] * vv[j];
        }
        __syncthreads();
    }
    #pragma unroll
    for (int i = 0; i < 4; ++i)
        #pragma unroll
        for (int j = 0; j < 4; ++j)
            out[((size_t)bofs * 89 + tx * 4 + j) * NPT + p0 + ty * 4 + i] = acc[i][j];
}

// ------------- kxx_local -------------
__global__ __launch_bounds__(256) void kxx_local_kernel(const float* __restrict__ X,
                                                        const float* __restrict__ nxb,
                                                        float* __restrict__ tmp, int bofs) {
    int r = blockIdx.y;
    int c0 = blockIdx.x * 16;
    const float* Xb = X + (size_t)bofs * CCH * NPT;
    __shared__ float Xs[32][104];
    int tid = threadIdx.x;
    int t0 = tid, t1 = tid + 256;
    int pl0 = t0 / 25, jj0 = t0 % 25;
    int pl1 = t1 / 25, jj1 = t1 % 25;
    int pidx0 = 40 + pl0 + 2;
    int jidx0 = (jj0 / 5) * 20 + pl0 + (jj0 % 5);
    int pidx1 = 40 + pl1 + 2;
    int jidx1 = (jj1 / 5) * 20 + pl1 + (jj1 % 5);
    float acc0 = 0.f, acc1 = 0.f;
    for (int ch0 = 0; ch0 < CCH; ch0 += 32) {
        for (int t = tid; t < 32 * 100; t += 256) {
            int ch = t / 100, i = t % 100;
            int s = i / 20, cc = i % 20;
            int gr = r + s - 2, gc = c0 - 2 + cc;
            float v = 0.f;
            if (gr >= 0 && gr < 64 && gc >= 0 && gc < 64)
                v = Xb[(size_t)(ch0 + ch) * NPT + gr * 64 + gc];
            Xs[ch][i] = v;
        }
        __syncthreads();
        #pragma unroll 8
        for (int kk = 0; kk < 32; ++kk) {
            acc0 += Xs[kk][pidx0] * Xs[kk][jidx0];
            if (t1 < 400) acc1 += Xs[kk][pidx1] * Xs[kk][jidx1];
        }
        __syncthreads();
    }
    {
        int p = r * 64 + c0 + pl0;
        int qr = r + jj0 / 5 - 2, qc = c0 + pl0 + jj0 % 5 - 2;
        float v = 0.f;
        if (qr >= 0 && qr < 64 && qc >= 0 && qc < 64) {
            int q = qr * 64 + qc;
            v = expf(acc0 / (nxb[p] * nxb[q] + CEPS) - 1.0f);
        }
        tmp[(size_t)jj0 * NPT + p] = v;
    }
    if (t1 < 400) {
        int p = r * 64 + c0 + pl1;
        int qr = r + jj1 / 5 - 2, qc = c0 + pl1 + jj1 % 5 - 2;
        float v = 0.f;
        if (qr >= 0 && qr < 64 && qc >= 0 && qc < 64) {
            int q = qr * 64 + qc;
            v = expf(acc1 / (nxb[p] * nxb[q] + CEPS) - 1.0f);
        }
        tmp[(size_t)jj1 * NPT + p] = v;
    }
}

// ------------- cov_local -------------
__global__ __launch_bounds__(256) void cov_local_kernel(const float* __restrict__ Brhs,
                                                        const float* __restrict__ tmp,
                                                        float* __restrict__ out, int bofs) {
    int r = blockIdx.y;
    int c0 = blockIdx.x * 16;
    const float* Ub = Brhs;
    __shared__ float Us[64][104];
    int tid = threadIdx.x;
    int t0 = tid, t1 = tid + 256;
    int pl0 = t0 / 25, jj0 = t0 % 25;
    int pl1 = t1 / 25, jj1 = t1 % 25;
    int pidx0 = 40 + pl0 + 2;
    int jidx0 = (jj0 / 5) * 20 + pl0 + (jj0 % 5);
    int pidx1 = 40 + pl1 + 2;
    int jidx1 = (jj1 / 5) * 20 + pl1 + (jj1 % 5);
    float acc0 = 0.f, acc1 = 0.f;
    for (int q0 = 0; q0 < NPT; q0 += 64) {
        for (int t = tid; t < 64 * 100; t += 256) {
            int qq = t / 100, i = t % 100;
            int s = i / 20, cc = i % 20;
            int gr = r + s - 2, gc = c0 - 2 + cc;
            float v = 0.f;
            if (gr >= 0 && gr < 64 && gc >= 0 && gc < 64)
                v = Ub[(size_t)(q0 + qq) * LDB + gr * 64 + gc];
            Us[qq][i] = v;
        }
        __syncthreads();
        #pragma unroll 8
        for (int kk = 0; kk < 64; ++kk) {
            acc0 += Us[kk][pidx0] * Us[kk][jidx0];
            if (t1 < 400) acc1 += Us[kk][pidx1] * Us[kk][jidx1];
        }
        __syncthreads();
    }
    {
        int p = r * 64 + c0 + pl0;
        int qr = r + jj0 / 5 - 2, qc = c0 + pl0 + jj0 % 5 - 2;
        float v = 0.f;
        if (qr >= 0 && qr < 64 && qc >= 0 && qc < 64)
            v = tmp[(size_t)jj0 * NPT + p] - acc0;
        out[((size_t)bofs * 89 + 64 + jj0) * NPT + p] = v;
    }
    if (t1 < 400) {
        int p = r * 64 + c0 + pl1;
        int qr = r + jj1 / 5 - 2, qc = c0 + pl1 + jj1 % 5 - 2;
        float v = 0.f;
        if (qr >= 0 && qr < 64 && qc >= 0 && qc < 64)
            v = tmp[(size_t)jj1 * NPT + p] - acc1;
        out[((size_t)bofs * 89 + 64 + jj1) * NPT + p] = v;
    }
}

extern "C" void kernel_launch(void* const* d_in, const int* in_sizes, int n_in,
                              void* d_out, int out_size, void* d_ws, size_t ws_size,
                              hipStream_t stream) {
    (void)in_sizes; (void)n_in; (void)out_size;
    const float* x  = (const float*)d_in[0];
    const float* y  = (const float*)d_in[1];
    const float* pw = (const float*)d_in[2];
    const float* pb = (const float*)d_in[3];
    float* out = (float*)d_out;
    float* ws  = (float*)d_ws;

    const size_t NEED = 2 * APSTR + (size_t)NPT * LDB + 2 * ILSTR + 4 * NPT + 2 * ((size_t)NPT * CCH / 2);
    if (ws_size < NEED * sizeof(float)) return;

    float* AmatP = ws;
    float* Brhs  = AmatP + 2 * APSTR;
    float* invL  = Brhs + (size_t)NPT * LDB;
    float* nx    = invL + 2 * ILSTR;
    float* ny    = nx + 2 * NPT;
    float* ysBuf = ny + 2 * NPT;
    ushort_t* ysH = (ushort_t*)ysBuf;
    ushort_t* ysL = ysH + (size_t)NPT * CCH;
    float* tmp = invL;   // aliases invL slot 0 (dead after that batch's solve)

    norms_kernel<<<dim3(16, 2), 256, 0, stream>>>(x, nx, 0);
    norms_kernel<<<dim3(16, 2), 256, 0, stream>>>(y, ny, 0);

    // K_yy grams -> packed lower Amat (per batch; ysBuf reused)
    for (int b = 0; b < 2; ++b) {
        split_kernel<<<dim3(8, 64, 1), 256, 0, stream>>>(y, ysH, ysL, b);
        gramA_packed_kernel<<<dim3(32, 32, 1), 256, 0, stream>>>(
            ysH, ysL, ny + (size_t)b * NPT, AmatP + (size_t)b * APSTR);
    }

    // blocked cholesky, both batches concurrently (z=2)
    potf2_packed_kernel<<<dim3(1, 1, 2), 256, 0, stream>>>(AmatP, invL, 0);
    for (int kb = 0; kb < NKB - 1; ++kb) {
        int nt = NKB - 1 - kb;
        trsm_packed_kernel<<<dim3(nt, 1, 2), 256, 0, stream>>>(AmatP, invL, kb);
        syrk_fact_packed_kernel<<<dim3(nt, nt, 2), 256, 0, stream>>>(AmatP, invL, kb);
    }

    // per batch: K_yx gram -> Brhs, features, right-looking fused solve, epilogues
    for (int b = 0; b < 2; ++b) {
        split_kernel<<<dim3(8, 64, 1), 256, 0, stream>>>(y, ysH, ysL, b);
        features_kernel<<<dim3(1024, 1), 256, 0, stream>>>(pw, pb, Brhs);
        gramX_kernel<<<dim3(32, 32, 1), 256, 0, stream>>>(
            ysH, ysL, x + (size_t)b * CCH * NPT, ny + (size_t)b * NPT, nx + (size_t)b * NPT, Brhs);

        trsm_rhs_kernel<<<dim3(65, 1, 1), 256, 0, stream>>>(Brhs, invL + (size_t)b * ILSTR);
        for (int kb = 0; kb < NKB - 1; ++kb) {
            solve_step_kernel<<<dim3(65, NKB - 1 - kb, 1), 256, 0, stream>>>(
                AmatP + (size_t)b * APSTR, Brhs, invL + (size_t)b * ILSTR, kb);
        }

        mu_kernel<<<dim3(64, 1, 1), 256, 0, stream>>>(Brhs, out, b);
        kxx_local_kernel<<<dim3(4, 64, 1), 256, 0, stream>>>(x, nx + (size_t)b * NPT, tmp, b);
        cov_local_kernel<<<dim3(4, 64, 1), 256, 0, stream>>>(Brhs, tmp, out, b);
    }
}